// Round 3
// baseline (3780.278 us; speedup 1.0000x reference)
//
#include <hip/hip_runtime.h>
#include <cstdio>
#include <math.h>

// Problem constants
#define BB 64
#define SS 512
#define HH 256
#define G4 1024   // 4*H
#define TT (BB*SS)  // 32768

__device__ __forceinline__ float sigf(float x){ return 1.0f/(1.0f+expf(-x)); }

// -------------------- prep: combined LSTM bias + zero h exchange buffer ----
__global__ void prep_kernel(const float* __restrict__ b_ih, const float* __restrict__ b_hh,
                            float* __restrict__ bcomb, float* __restrict__ hglob){
    int i = blockIdx.x*blockDim.x + threadIdx.x;
    if (i < G4) bcomb[i] = b_ih[i] + b_hh[i];
    hglob[i] = 0.f;                       // 128*256 = 32768 = 2*64*256 exactly
}

// -------------------- generic fp32 GEMM: C[M,N] = A[M,K] * B[N,K]^T + bias -
__global__ __launch_bounds__(256) void gemm_nt(
    const float* __restrict__ A, const float* __restrict__ Bw,
    const float* __restrict__ bias, float* __restrict__ C,
    int N, const int* __restrict__ lengths)
{
    const int K = 256;
    int m0 = blockIdx.y * 64, n0 = blockIdx.x * 64;
    if (lengths){ int b = m0 >> 9, t0 = m0 & 511; if (t0 >= lengths[b]) return; }
    __shared__ float As[16][64];
    __shared__ float Bs[16][64];
    int tid = threadIdx.x;
    int tx = tid & 15, ty = tid >> 4;
    int lr = tid >> 2, lk = (tid & 3) << 2;
    float acc[4][4] = {};
    const float* Aptr = A + (size_t)(m0 + lr)*K + lk;
    const float* Bptr = Bw + (size_t)(n0 + lr)*K + lk;
    for (int k0 = 0; k0 < K; k0 += 16) {
        float4 av = *(const float4*)(Aptr + k0);
        float4 bv = *(const float4*)(Bptr + k0);
        __syncthreads();
        As[lk+0][lr]=av.x; As[lk+1][lr]=av.y; As[lk+2][lr]=av.z; As[lk+3][lr]=av.w;
        Bs[lk+0][lr]=bv.x; Bs[lk+1][lr]=bv.y; Bs[lk+2][lr]=bv.z; Bs[lk+3][lr]=bv.w;
        __syncthreads();
        #pragma unroll
        for (int kk = 0; kk < 16; ++kk) {
            float4 a4 = *(const float4*)&As[kk][ty<<2];
            float4 b4 = *(const float4*)&Bs[kk][tx<<2];
            float av_[4] = {a4.x, a4.y, a4.z, a4.w};
            float bv_[4] = {b4.x, b4.y, b4.z, b4.w};
            #pragma unroll
            for (int i=0;i<4;i++)
                #pragma unroll
                for (int j=0;j<4;j++)
                    acc[i][j] = fmaf(av_[i], bv_[j], acc[i][j]);
        }
    }
    int col = n0 + (tx<<2);
    float4 bb4 = bias ? *(const float4*)&bias[col] : make_float4(0.f,0.f,0.f,0.f);
    #pragma unroll
    for (int i=0;i<4;i++){
        int row = m0 + (ty<<2) + i;
        float4 o;
        o.x = acc[i][0]+bb4.x; o.y = acc[i][1]+bb4.y; o.z = acc[i][2]+bb4.z; o.w = acc[i][3]+bb4.w;
        *(float4*)&C[(size_t)row*N + col] = o;
    }
}

// -------------------- per-row LayerNorm (optional residual add, optional ReLU)
__global__ __launch_bounds__(256) void ln_act(
    float* __restrict__ X, const float* __restrict__ add,
    const float* __restrict__ gg, const float* __restrict__ bb,
    const int* __restrict__ lengths, int relu)
{
    int row = blockIdx.x;
    { int b = row >> 9, t = row & 511; if (t >= lengths[b]) return; }
    int tid = threadIdx.x;
    __shared__ float red[8];
    size_t idx = (size_t)row*HH + tid;
    float v = X[idx];
    if (add) v += add[idx];
    float s = v, q = v*v;
    #pragma unroll
    for (int m=32;m>=1;m>>=1){ s += __shfl_xor(s,m); q += __shfl_xor(q,m); }
    if ((tid&63)==0){ red[tid>>6]=s; red[4+(tid>>6)]=q; }
    __syncthreads();
    s = red[0]+red[1]+red[2]+red[3]; q = red[4]+red[5]+red[6]+red[7];
    float mean = s*(1.f/HH);
    float var  = q*(1.f/HH) - mean*mean;
    float rstd = rsqrtf(var + 1e-5f);
    float o = (v-mean)*rstd*gg[tid] + bb[tid];
    if (relu) o = fmaxf(o, 0.f);
    X[idx] = o;
}

// -------------------- LSTM recurrence, tag-in-data exchange ---------------
// 64 blocks = 8 batch-groups (g) x 8 hidden-partitions (p). w_hh slice lives
// in VGPRs (64 floats/thread). Cross-block h exchange: publisher mangles the
// 3 LSBs of each float's mantissa with tag ((s+1)&7)^5 and stores sc1
// (relaxed agent atomic). Consumers poll-load remote slices and validate the
// tag per float -- no counter barrier, no fences, no store drain. 2 slots x
// 3-bit tags are collision-free vs both prior slot occupants and the zeroed
// init. Intra-block sync uses lgkmcnt-only raw barriers so sc1 store acks /
// Zx prefetch never block the critical path.
__global__ __launch_bounds__(512) void lstm_kernel(
    const float* __restrict__ Zx, const float* __restrict__ whh,
    const int* __restrict__ lengths, float* __restrict__ hglob,
    float* __restrict__ out)
{
    int bid = blockIdx.x;
    int g = bid & 7, p = bid >> 3;
    int tid = threadIdx.x;
    __shared__ __align__(16) float hs[8][256];     // full h for the 8 group rows
    __shared__ float zred[4][8][128];              // k-split partial z

    int wv = tid >> 6, lane = tid & 63;
    int jh = wv & 1, kq2 = wv >> 1;
    int j = jh*64 + lane;               // local z column 0..127 (gate q=j>>5, dim dd=j&31)

    // w_hh slice in registers: row (q*256 + p*32 + dd), k-range [kq2*64, +64)
    float wreg[64];
    {
        int q = j >> 5, dd = j & 31;
        const float* srcw = whh + (size_t)(q*256 + p*32 + dd)*256 + kq2*64;
        #pragma unroll
        for (int c=0;c<16;c++){
            float4 w4 = *(const float4*)(srcw + c*4);
            wreg[c*4+0]=w4.x; wreg[c*4+1]=w4.y; wreg[c*4+2]=w4.z; wreg[c*4+3]=w4.w;
        }
    }
    int Tg = 0;
    #pragma unroll
    for (int r=0;r<8;r++) Tg = max(Tg, lengths[g*8+r]);

    int gr = tid >> 5, gd = tid & 31;   // gate mapping (tid<256): row gr, dim gd
    int row = g*8 + gr;
    float creg = 0.f;

    unsigned long long* hgl64 = (unsigned long long*)hglob;
    unsigned long long* hsd   = (unsigned long long*)hs;

    // poll-thread constant decode (tid>=256): u64 chunks i0, i0+256, i0+512, i0+768
    int i0 = tid - 256;
    int ia = i0, ib = i0+256, ic = i0+512, id2 = i0+768;
    int sa = ia>>7, sb = ib>>7, sc2 = ic>>7, sd = id2>>7;
    int pa = sa + (sa>=p), pb = sb + (sb>=p), pc = sc2 + (sc2>=p), pd = sd + (sd>=p);
    int ra = (ia>>4)&7, rb=(ib>>4)&7, rc=(ic>>4)&7, rd=(id2>>4)&7;
    int qa = ia&15, qb=ib&15, qc=ic&15, qd=id2&15;
    size_t oa = (size_t)ra*128 + pa*16 + qa;
    size_t ob = (size_t)rb*128 + pb*16 + qb;
    size_t oc = (size_t)rc*128 + pc*16 + qc;
    size_t od = (size_t)rd*128 + pd*16 + qd;
    bool has4 = (i0 < 128);

    for (int i = tid; i < 8*256; i += 512) ((float*)hs)[i] = 0.f;
    __syncthreads();

    // prefetch Zx gate slice for step 0
    float zx0=0.f, zx1=0.f, zx2=0.f, zx3=0.f;
    size_t zbase = (size_t)row*SS*G4 + (size_t)(p*32 + gd);
    if (tid < 256 && Tg > 0){
        zx0 = Zx[zbase +   0];
        zx1 = Zx[zbase + 256];
        zx2 = Zx[zbase + 512];
        zx3 = Zx[zbase + 768];
    }

    for (int s = 0; s < Tg; ++s) {
        // ---- z partials: acc[r] = sum_{k in quarter kq2} hs[r][k]*w[j][k]
        float acc[8] = {0.f,0.f,0.f,0.f,0.f,0.f,0.f,0.f};
        #pragma unroll
        for (int c=0;c<16;c++){
            int kb = kq2*64 + c*4;
            #pragma unroll
            for (int r=0;r<8;r++){
                float4 h4 = *(const float4*)&hs[r][kb];
                acc[r] = fmaf(h4.x,wreg[c*4+0], fmaf(h4.y,wreg[c*4+1],
                         fmaf(h4.z,wreg[c*4+2], fmaf(h4.w,wreg[c*4+3], acc[r]))));
            }
        }
        #pragma unroll
        for (int r=0;r<8;r++) zred[kq2][r][j] = acc[r];

        asm volatile("s_waitcnt lgkmcnt(0)" ::: "memory");
        __builtin_amdgcn_s_barrier();                       // A: zred ready, hs free
        asm volatile("" ::: "memory");

        int buf = (s+1) & 1;
        unsigned tag = (((unsigned)(s+1)) & 7u) ^ 5u;
        if (tid < 256) {
            float z0,z1,z2,z3;
            {
                int j0 = gd, j1 = 32+gd, j2 = 64+gd, j3 = 96+gd;
                z0 = zred[0][gr][j0]+zred[1][gr][j0]+zred[2][gr][j0]+zred[3][gr][j0] + zx0;
                z1 = zred[0][gr][j1]+zred[1][gr][j1]+zred[2][gr][j1]+zred[3][gr][j1] + zx1;
                z2 = zred[0][gr][j2]+zred[1][gr][j2]+zred[2][gr][j2]+zred[3][gr][j2] + zx2;
                z3 = zred[0][gr][j3]+zred[1][gr][j3]+zred[2][gr][j3]+zred[3][gr][j3] + zx3;
            }
            // prefetch next step's Zx (independent; overlaps gate math + exchange)
            if (s+1 < Tg){
                size_t zb = zbase + (size_t)(s+1)*G4;
                zx0 = Zx[zb +   0];
                zx1 = Zx[zb + 256];
                zx2 = Zx[zb + 512];
                zx3 = Zx[zb + 768];
            }
            creg = sigf(z1)*creg + sigf(z0)*tanhf(z2);
            float hvv = sigf(z3)*tanhf(creg);
            unsigned hb = (__float_as_uint(hvv) & ~7u) | tag;
            float hm = __uint_as_float(hb);
            // publish mangled h to coherence point; own slice straight to LDS
            __hip_atomic_store(&hglob[(size_t)buf*16384 + (size_t)row*256 + p*32 + gd],
                               hm, __ATOMIC_RELAXED, __HIP_MEMORY_SCOPE_AGENT);
            out[((size_t)row*SS + s)*HH + p*32 + gd] = hvv;
            hs[gr][p*32 + gd] = hm;
        } else {
            // poll 7 remote slices (896 u64 over 256 threads), validate tags
            unsigned long long* base = hgl64 + (size_t)buf*8192 + (size_t)g*1024;
            unsigned long long va = __hip_atomic_load(&base[oa], __ATOMIC_RELAXED, __HIP_MEMORY_SCOPE_AGENT);
            unsigned long long vb = __hip_atomic_load(&base[ob], __ATOMIC_RELAXED, __HIP_MEMORY_SCOPE_AGENT);
            unsigned long long vc = __hip_atomic_load(&base[oc], __ATOMIC_RELAXED, __HIP_MEMORY_SCOPE_AGENT);
            unsigned long long vd = 0;
            if (has4) vd = __hip_atomic_load(&base[od], __ATOMIC_RELAXED, __HIP_MEMORY_SCOPE_AGENT);
            bool da=false, db=false, dc=false, dd=!has4;
            while (!(da && db && dc && dd)){
                if (!da){
                    if ((((unsigned)va&7u)==tag) && (((unsigned)(va>>32)&7u)==tag)){ hsd[oa]=va; da=true; }
                    else va = __hip_atomic_load(&base[oa], __ATOMIC_RELAXED, __HIP_MEMORY_SCOPE_AGENT);
                }
                if (!db){
                    if ((((unsigned)vb&7u)==tag) && (((unsigned)(vb>>32)&7u)==tag)){ hsd[ob]=vb; db=true; }
                    else vb = __hip_atomic_load(&base[ob], __ATOMIC_RELAXED, __HIP_MEMORY_SCOPE_AGENT);
                }
                if (!dc){
                    if ((((unsigned)vc&7u)==tag) && (((unsigned)(vc>>32)&7u)==tag)){ hsd[oc]=vc; dc=true; }
                    else vc = __hip_atomic_load(&base[oc], __ATOMIC_RELAXED, __HIP_MEMORY_SCOPE_AGENT);
                }
                if (!dd){
                    if ((((unsigned)vd&7u)==tag) && (((unsigned)(vd>>32)&7u)==tag)){ hsd[od]=vd; dd=true; }
                    else vd = __hip_atomic_load(&base[od], __ATOMIC_RELAXED, __HIP_MEMORY_SCOPE_AGENT);
                }
            }
        }
        asm volatile("s_waitcnt lgkmcnt(0)" ::: "memory");
        __builtin_amdgcn_s_barrier();                       // B: hs(s+1) complete
        asm volatile("" ::: "memory");
    }
}

// -------------------- attention: one block per (b, head), flash-style ----
__global__ __launch_bounds__(256) void attn_kernel(
    const float* __restrict__ qkv, const int* __restrict__ lengths, float* __restrict__ ctx)
{
    int bh = blockIdx.x; int b = bh >> 3, h = bh & 7;
    int len = lengths[b];
    int tid = threadIdx.x;
    __shared__ float Ks[512][32];
    __shared__ float Vs[512][32];
    for (int i = tid; i < len*32; i += 256){
        int s = i >> 5, d = i & 31;
        size_t base = ((size_t)b*512 + s)*768 + h*32 + d;
        Ks[s][d] = qkv[base + 256];
        Vs[s][d] = qkv[base + 512];
    }
    __syncthreads();
    const float rs = 0.1767766952966369f;   // 1/sqrt(32)
    for (int q0 = 0; q0 < 512; q0 += 256){
        int q = q0 + tid;
        if (q >= len) continue;
        float qr[32];
        size_t qb = ((size_t)b*512 + q)*768 + h*32;
        #pragma unroll
        for (int d=0; d<32; d+=4){
            float4 t4 = *(const float4*)&qkv[qb+d];
            qr[d]=t4.x; qr[d+1]=t4.y; qr[d+2]=t4.z; qr[d+3]=t4.w;
        }
        float m = -3.4e38f, l = 0.f, acc[32];
        #pragma unroll
        for (int d=0;d<32;d++) acc[d]=0.f;
        for (int k=0;k<len;k++){
            float sc = 0.f;
            #pragma unroll
            for (int d=0;d<32;d+=4){
                float4 kv = *(const float4*)&Ks[k][d];
                sc += qr[d]*kv.x + qr[d+1]*kv.y + qr[d+2]*kv.z + qr[d+3]*kv.w;
            }
            sc *= rs;
            float nm = fmaxf(m, sc);
            float f  = expf(m - nm);
            float pc = expf(sc - nm);
            l = l*f + pc;
            #pragma unroll
            for (int d=0;d<32;d+=4){
                float4 vv = *(const float4*)&Vs[k][d];
                acc[d]   = acc[d]*f   + pc*vv.x;
                acc[d+1] = acc[d+1]*f + pc*vv.y;
                acc[d+2] = acc[d+2]*f + pc*vv.z;
                acc[d+3] = acc[d+3]*f + pc*vv.w;
            }
            m = nm;
        }
        float inv = 1.f/l;
        size_t cb = ((size_t)b*512 + q)*256 + h*32;
        #pragma unroll
        for (int d=0;d<32;d+=4){
            float4 o; o.x=acc[d]*inv; o.y=acc[d+1]*inv; o.z=acc[d+2]*inv; o.w=acc[d+3]*inv;
            *(float4*)&ctx[cb+d] = o;
        }
    }
}

// -------------------- Switch MoE (top-1) + LN2, one block per valid token -
__global__ __launch_bounds__(256) void moe_kernel(
    const float* __restrict__ src, const float* __restrict__ rw,
    const float* __restrict__ w1, const float* __restrict__ b1,
    const float* __restrict__ w2, const float* __restrict__ b2,
    const float* __restrict__ g2, const float* __restrict__ bt2,
    const int* __restrict__ lengths, float* __restrict__ out)
{
    int row = blockIdx.x;
    { int bb = row >> 9, t = row & 511; if (t >= lengths[bb]) return; }
    int tid = threadIdx.x;
    __shared__ float sv[256];
    __shared__ float hv[256];
    __shared__ float red[8];
    __shared__ float lsh[8];
    __shared__ int eidx;
    float x = src[(size_t)row*256 + tid];
    sv[tid] = x;
    __syncthreads();
    for (int e=0; e<5; ++e){
        float v = x * rw[tid*5 + e];
        #pragma unroll
        for (int m=32;m>=1;m>>=1) v += __shfl_xor(v,m);
        if ((tid&63)==0) red[tid>>6] = v;
        __syncthreads();
        if (tid==0) lsh[e] = red[0]+red[1]+red[2]+red[3];
        __syncthreads();
    }
    if (tid==0){
        float mx = lsh[0]; int ix = 0;
        for (int e=1;e<5;e++) if (lsh[e] > mx){ mx = lsh[e]; ix = e; }
        float ssum = 0.f;
        for (int e=0;e<5;e++) ssum += expf(lsh[e]-mx);
        lsh[5] = 1.0f/ssum;
        eidx = ix;
    }
    __syncthreads();
    int e = eidx; float gate = lsh[5];
    const float* W1 = w1 + (size_t)e*65536;
    float acc = b1[e*256 + tid];
    for (int d=0; d<256; ++d) acc = fmaf(sv[d], W1[(size_t)d*256 + tid], acc);
    hv[tid] = fmaxf(acc, 0.f);
    __syncthreads();
    const float* W2 = w2 + (size_t)e*65536;
    float acc2 = b2[e*256 + tid];
    for (int d=0; d<256; ++d) acc2 = fmaf(hv[d], W2[(size_t)d*256 + tid], acc2);
    float r = x + gate*acc2;
    float s = r, q = r*r;
    #pragma unroll
    for (int m=32;m>=1;m>>=1){ s += __shfl_xor(s,m); q += __shfl_xor(q,m); }
    __syncthreads();
    if ((tid&63)==0){ red[tid>>6]=s; red[4+(tid>>6)]=q; }
    __syncthreads();
    s = red[0]+red[1]+red[2]+red[3]; q = red[4]+red[5]+red[6]+red[7];
    float mean = s*(1.f/256.f), var = q*(1.f/256.f)-mean*mean, rstd = rsqrtf(var+1e-5f);
    out[(size_t)row*256 + tid] = (r-mean)*rstd*g2[tid] + bt2[tid];
}

// -------------------- masked mean pool ------------------------------------
__global__ __launch_bounds__(256) void pool_kernel(
    const float* __restrict__ out2, const int* __restrict__ lengths, float* __restrict__ pooled)
{
    int b = blockIdx.x, d = threadIdx.x;
    int len = lengths[b];
    float s = 0.f;
    for (int t=0;t<len;t++) s += out2[((size_t)b*512 + t)*256 + d];
    pooled[b*256 + d] = s / (float)len;
}

// -------------------- classifier head -------------------------------------
__global__ __launch_bounds__(256) void cls_kernel(
    const float* __restrict__ pooled, const float* __restrict__ w1,
    const float* __restrict__ b1, const float* __restrict__ lg, const float* __restrict__ lb,
    const float* __restrict__ w2, const float* __restrict__ b2, float* __restrict__ outp)
{
    int b = blockIdx.x, j = threadIdx.x;
    __shared__ float pv[256];
    __shared__ float red[8];
    pv[j] = pooled[b*256 + j];
    __syncthreads();
    float acc = b1[j];
    for (int d=0; d<256; d+=4){
        float4 p4 = *(const float4*)&pv[d];
        const float* wr = &w1[(size_t)j*256 + d];
        acc += p4.x*wr[0] + p4.y*wr[1] + p4.z*wr[2] + p4.w*wr[3];
    }
    float s = acc, q = acc*acc;
    #pragma unroll
    for (int m=32;m>=1;m>>=1){ s += __shfl_xor(s,m); q += __shfl_xor(q,m); }
    int wid = j>>6;
    if ((j&63)==0){ red[wid]=s; red[4+wid]=q; }
    __syncthreads();
    s = red[0]+red[1]+red[2]+red[3]; q = red[4]+red[5]+red[6]+red[7];
    float mean = s*(1.f/256.f), var = q*(1.f/256.f)-mean*mean, rstd = rsqrtf(var+1e-5f);
    float h1v = fmaxf((acc-mean)*rstd*lg[j]+lb[j], 0.f);
    float pr = h1v * w2[j];
    __syncthreads();
    #pragma unroll
    for (int m=32;m>=1;m>>=1) pr += __shfl_xor(pr,m);
    if ((j&63)==0) red[wid] = pr;
    __syncthreads();
    if (j==0) outp[b] = red[0]+red[1]+red[2]+red[3] + b2[0];
}

// ==========================================================================
extern "C" void kernel_launch(void* const* d_in, const int* in_sizes, int n_in,
                              void* d_out, int out_size, void* d_ws, size_t ws_size,
                              hipStream_t stream)
{
    const float* x       = (const float*)d_in[0];
    const int*   lengths = (const int*)  d_in[1];
    const float* fe_w    = (const float*)d_in[2];
    const float* fe_b    = (const float*)d_in[3];
    const float* fe_ln_g = (const float*)d_in[4];
    const float* fe_ln_b = (const float*)d_in[5];
    const float* w_ih    = (const float*)d_in[6];
    const float* w_hh    = (const float*)d_in[7];
    const float* b_ih    = (const float*)d_in[8];
    const float* b_hh    = (const float*)d_in[9];
    const float* attn_w  = (const float*)d_in[10];
    const float* attn_b  = (const float*)d_in[11];
    const float* attn_ow = (const float*)d_in[12];
    const float* attn_ob = (const float*)d_in[13];
    const float* ln1_g   = (const float*)d_in[14];
    const float* ln1_b   = (const float*)d_in[15];
    const float* router_w= (const float*)d_in[16];
    const float* e_w1    = (const float*)d_in[17];
    const float* e_b1    = (const float*)d_in[18];
    const float* e_w2    = (const float*)d_in[19];
    const float* e_b2    = (const float*)d_in[20];
    const float* ln2_g   = (const float*)d_in[21];
    const float* ln2_b   = (const float*)d_in[22];
    const float* cl_w1   = (const float*)d_in[23];
    const float* cl_b1   = (const float*)d_in[24];
    const float* cl_ln_g = (const float*)d_in[25];
    const float* cl_ln_b = (const float*)d_in[26];
    const float* cl_w2   = (const float*)d_in[27];
    const float* cl_b2   = (const float*)d_in[28];
    float* outp = (float*)d_out;

    // workspace layout (floats)
    const size_t NEED = (size_t)50381832 * 4;
    if (ws_size < NEED){
        fprintf(stderr, "kernel_launch: ws too small (%zu < %zu)\n", ws_size, NEED);
        return;
    }
    float* W     = (float*)d_ws;
    float* h0    = W;                    // [T,256]   32MB
    float* Zx    = W + 8388608;          // [T,1024] 128MB
    float* lstm  = W + 41943040;         // [T,256]   32MB
    float* hglob = W + 50331648;         // [2,64,256]
    float* pooled= W + 50364416;         // [64,256]
    float* bcomb = W + 50380800;         // [1024]
    // aliases into dead regions
    float* qkv  = Zx;                    // [T,768] (after LSTM consumes Zx)
    float* ctx  = Zx + 25165824;         // [T,256]
    float* aop  = h0;                    // [T,256] (h0 dead after Zx GEMM)
    float* src  = lstm;                  // LN1 in-place
    float* out2 = Zx;                    // [T,256] (qkv/ctx dead)

    prep_kernel<<<dim3(128), 256, 0, stream>>>(b_ih, b_hh, bcomb, hglob);
    // feature extractor GEMM + LN + ReLU
    gemm_nt<<<dim3(4,512), 256, 0, stream>>>(x, fe_w, fe_b, h0, 256, lengths);
    ln_act<<<dim3(32768), 256, 0, stream>>>(h0, nullptr, fe_ln_g, fe_ln_b, lengths, 1);
    // LSTM input projection for all timesteps
    gemm_nt<<<dim3(16,512), 256, 0, stream>>>(h0, w_ih, bcomb, Zx, 1024, lengths);
    // recurrent LSTM
    lstm_kernel<<<dim3(64), 512, 0, stream>>>(Zx, w_hh, lengths, hglob, lstm);
    // attention
    gemm_nt<<<dim3(12,512), 256, 0, stream>>>(lstm, attn_w, attn_b, qkv, 768, lengths);
    attn_kernel<<<dim3(512), 256, 0, stream>>>(qkv, lengths, ctx);
    gemm_nt<<<dim3(4,512), 256, 0, stream>>>(ctx, attn_ow, attn_ob, aop, 256, lengths);
    // post-norm residual LN1 (in-place into lstm -> src)
    ln_act<<<dim3(32768), 256, 0, stream>>>(src, aop, ln1_g, ln1_b, lengths, 0);
    // MoE + LN2
    moe_kernel<<<dim3(32768), 256, 0, stream>>>(src, router_w, e_w1, e_b1, e_w2, e_b2,
                                                ln2_g, ln2_b, lengths, out2);
    // masked mean pool + classifier
    pool_kernel<<<dim3(64), 256, 0, stream>>>(out2, lengths, pooled);
    cls_kernel<<<dim3(64), 256, 0, stream>>>(pooled, cl_w1, cl_b1, cl_ln_g, cl_ln_b,
                                             cl_w2, cl_b2, outp);
}

// Round 4
// 3251.068 us; speedup vs baseline: 1.1628x; 1.1628x over previous
//
#include <hip/hip_runtime.h>
#include <cstdio>
#include <math.h>

// Problem constants
#define BB 64
#define SS 512
#define HH 256
#define G4 1024   // 4*H
#define TT (BB*SS)  // 32768

typedef _Float16 h2 __attribute__((ext_vector_type(2)));

__device__ __forceinline__ float sigf(float x){ return 1.0f/(1.0f+expf(-x)); }

// -------------------- prep: combined LSTM bias + zero h exchange + cnt -----
__global__ void prep_kernel(const float* __restrict__ b_ih, const float* __restrict__ b_hh,
                            float* __restrict__ bcomb, float* __restrict__ hglob,
                            unsigned* __restrict__ cnt){
    int i = blockIdx.x*blockDim.x + threadIdx.x;
    if (i < G4) bcomb[i] = b_ih[i] + b_hh[i];
    if (i < 8)  cnt[i] = 0u;
    hglob[i] = 0.f;                       // 128 blocks x 256 = 32768 = 2*64*256
}

// -------------------- generic fp32 GEMM: C[M,N] = A[M,K] * B[N,K]^T + bias -
__global__ __launch_bounds__(256) void gemm_nt(
    const float* __restrict__ A, const float* __restrict__ Bw,
    const float* __restrict__ bias, float* __restrict__ C,
    int N, const int* __restrict__ lengths)
{
    const int K = 256;
    int m0 = blockIdx.y * 64, n0 = blockIdx.x * 64;
    if (lengths){ int b = m0 >> 9, t0 = m0 & 511; if (t0 >= lengths[b]) return; }
    __shared__ float As[16][64];
    __shared__ float Bs[16][64];
    int tid = threadIdx.x;
    int tx = tid & 15, ty = tid >> 4;
    int lr = tid >> 2, lk = (tid & 3) << 2;
    float acc[4][4] = {};
    const float* Aptr = A + (size_t)(m0 + lr)*K + lk;
    const float* Bptr = Bw + (size_t)(n0 + lr)*K + lk;
    for (int k0 = 0; k0 < K; k0 += 16) {
        float4 av = *(const float4*)(Aptr + k0);
        float4 bv = *(const float4*)(Bptr + k0);
        __syncthreads();
        As[lk+0][lr]=av.x; As[lk+1][lr]=av.y; As[lk+2][lr]=av.z; As[lk+3][lr]=av.w;
        Bs[lk+0][lr]=bv.x; Bs[lk+1][lr]=bv.y; Bs[lk+2][lr]=bv.z; Bs[lk+3][lr]=bv.w;
        __syncthreads();
        #pragma unroll
        for (int kk = 0; kk < 16; ++kk) {
            float4 a4 = *(const float4*)&As[kk][ty<<2];
            float4 b4 = *(const float4*)&Bs[kk][tx<<2];
            float av_[4] = {a4.x, a4.y, a4.z, a4.w};
            float bv_[4] = {b4.x, b4.y, b4.z, b4.w};
            #pragma unroll
            for (int i=0;i<4;i++)
                #pragma unroll
                for (int j=0;j<4;j++)
                    acc[i][j] = fmaf(av_[i], bv_[j], acc[i][j]);
        }
    }
    int col = n0 + (tx<<2);
    float4 bb4 = bias ? *(const float4*)&bias[col] : make_float4(0.f,0.f,0.f,0.f);
    #pragma unroll
    for (int i=0;i<4;i++){
        int row = m0 + (ty<<2) + i;
        float4 o;
        o.x = acc[i][0]+bb4.x; o.y = acc[i][1]+bb4.y; o.z = acc[i][2]+bb4.z; o.w = acc[i][3]+bb4.w;
        *(float4*)&C[(size_t)row*N + col] = o;
    }
}

// -------------------- per-row LayerNorm (optional residual add, optional ReLU)
__global__ __launch_bounds__(256) void ln_act(
    float* __restrict__ X, const float* __restrict__ add,
    const float* __restrict__ gg, const float* __restrict__ bb,
    const int* __restrict__ lengths, int relu)
{
    int row = blockIdx.x;
    { int b = row >> 9, t = row & 511; if (t >= lengths[b]) return; }
    int tid = threadIdx.x;
    __shared__ float red[8];
    size_t idx = (size_t)row*HH + tid;
    float v = X[idx];
    if (add) v += add[idx];
    float s = v, q = v*v;
    #pragma unroll
    for (int m=32;m>=1;m>>=1){ s += __shfl_xor(s,m); q += __shfl_xor(q,m); }
    if ((tid&63)==0){ red[tid>>6]=s; red[4+(tid>>6)]=q; }
    __syncthreads();
    s = red[0]+red[1]+red[2]+red[3]; q = red[4]+red[5]+red[6]+red[7];
    float mean = s*(1.f/HH);
    float var  = q*(1.f/HH) - mean*mean;
    float rstd = rsqrtf(var + 1e-5f);
    float o = (v-mean)*rstd*gg[tid] + bb[tid];
    if (relu) o = fmaxf(o, 0.f);
    X[idx] = o;
}

// -------------------- LSTM recurrence, tag-in-data exchange, fp16 z-GEMM --
// 64 blocks = 8 batch-groups (g) x 8 hidden-partitions (p). w_hh slice in
// half2 VGPRs; recurrent h kept in LDS as fp16 (z via v_dot2_f32_f16 ->
// halves both LDS-pipe issue and VALU of the z-phase). Cross-block exchange
// unchanged from round 3: fp32 payload with 3-LSB mantissa tag, relaxed
// agent-scope (sc1) atomics, no fences/counters; pollers convert to fp16
// when landing into LDS.
__global__ __launch_bounds__(512) void lstm_kernel(
    const float* __restrict__ Zx, const float* __restrict__ whh,
    const int* __restrict__ lengths, float* __restrict__ hglob,
    float* __restrict__ out)
{
    int bid = blockIdx.x;
    int g = bid & 7, p = bid >> 3;
    int tid = threadIdx.x;
    __shared__ __align__(16) _Float16 hs[8][256];  // 4KB, fp16 h for 8 rows
    __shared__ float zred[4][8][128];              // k-split partial z

    int wv = tid >> 6, lane = tid & 63;
    int jh = wv & 1, kq2 = wv >> 1;
    int j = jh*64 + lane;               // local z column 0..127

    // w_hh slice in half2 regs: row (q*256+p*32+dd), k in [kq2*64, +64)
    h2 wreg[32];
    {
        int q = j >> 5, dd = j & 31;
        const float* srcw = whh + (size_t)(q*256 + p*32 + dd)*256 + kq2*64;
        #pragma unroll
        for (int c=0;c<16;c++){
            float4 w4 = *(const float4*)(srcw + c*4);
            h2 a; a.x = (_Float16)w4.x; a.y = (_Float16)w4.y;
            h2 b; b.x = (_Float16)w4.z; b.y = (_Float16)w4.w;
            wreg[2*c] = a; wreg[2*c+1] = b;
        }
    }
    int Tg = 0;
    #pragma unroll
    for (int r=0;r<8;r++) Tg = max(Tg, lengths[g*8+r]);

    int gr = tid >> 5, gd = tid & 31;   // gate mapping (tid<256)
    int row = g*8 + gr;
    float creg = 0.f;

    unsigned long long* hgl64 = (unsigned long long*)hglob;
    unsigned* hsu = (unsigned*)hs;      // half2-packed view, 128 u32 per row

    // poll-thread decode (tid>=256): u32-pair chunks i0, +256, +512, +768
    int i0 = tid - 256;
    int ia = i0, ib = i0+256, ic = i0+512, id2 = i0+768;
    int sa = ia>>7, sb = ib>>7, sc2 = ic>>7, sd = id2>>7;
    int pa = sa + (sa>=p), pb = sb + (sb>=p), pc = sc2 + (sc2>=p), pd = sd + (sd>=p);
    int ra = (ia>>4)&7, rb=(ib>>4)&7, rc=(ic>>4)&7, rd=(id2>>4)&7;
    int qa = ia&15, qb=ib&15, qc=ic&15, qd=id2&15;
    size_t oa = (size_t)ra*128 + pa*16 + qa;
    size_t ob = (size_t)rb*128 + pb*16 + qb;
    size_t oc = (size_t)rc*128 + pc*16 + qc;
    size_t od = (size_t)rd*128 + pd*16 + qd;
    bool has4 = (i0 < 128);

    for (int i = tid; i < 1024; i += 512) hsu[i] = 0u;
    __syncthreads();

    // prefetch Zx gate slice for step 0
    float zx0=0.f, zx1=0.f, zx2=0.f, zx3=0.f;
    size_t zbase = (size_t)row*SS*G4 + (size_t)(p*32 + gd);
    if (tid < 256 && Tg > 0){
        zx0 = Zx[zbase +   0];
        zx1 = Zx[zbase + 256];
        zx2 = Zx[zbase + 512];
        zx3 = Zx[zbase + 768];
    }

    union U16 { float4 f4; h2 h[4]; };

    for (int s = 0; s < Tg; ++s) {
        // ---- z partials via dot2: acc[r] = sum_{k in quarter} hs[r][k]*w[j][k]
        float acc[8] = {0.f,0.f,0.f,0.f,0.f,0.f,0.f,0.f};
        #pragma unroll
        for (int c=0;c<8;c++){
            #pragma unroll
            for (int r=0;r<8;r++){
                U16 u;
                u.f4 = *(const float4*)((const char*)hs + r*512 + kq2*128 + c*16);
                acc[r] = __builtin_amdgcn_fdot2(u.h[0], wreg[c*4+0], acc[r], false);
                acc[r] = __builtin_amdgcn_fdot2(u.h[1], wreg[c*4+1], acc[r], false);
                acc[r] = __builtin_amdgcn_fdot2(u.h[2], wreg[c*4+2], acc[r], false);
                acc[r] = __builtin_amdgcn_fdot2(u.h[3], wreg[c*4+3], acc[r], false);
            }
        }
        #pragma unroll
        for (int r=0;r<8;r++) zred[kq2][r][j] = acc[r];

        asm volatile("s_waitcnt lgkmcnt(0)" ::: "memory");
        __builtin_amdgcn_s_barrier();                       // A: zred ready, hs free
        asm volatile("" ::: "memory");

        int buf = (s+1) & 1;
        unsigned tag = (((unsigned)(s+1)) & 7u) ^ 5u;
        if (tid < 256) {
            float z0,z1,z2,z3;
            {
                int j0 = gd, j1 = 32+gd, j2 = 64+gd, j3 = 96+gd;
                z0 = zred[0][gr][j0]+zred[1][gr][j0]+zred[2][gr][j0]+zred[3][gr][j0] + zx0;
                z1 = zred[0][gr][j1]+zred[1][gr][j1]+zred[2][gr][j1]+zred[3][gr][j1] + zx1;
                z2 = zred[0][gr][j2]+zred[1][gr][j2]+zred[2][gr][j2]+zred[3][gr][j2] + zx2;
                z3 = zred[0][gr][j3]+zred[1][gr][j3]+zred[2][gr][j3]+zred[3][gr][j3] + zx3;
            }
            if (s+1 < Tg){
                size_t zb = zbase + (size_t)(s+1)*G4;
                zx0 = Zx[zb +   0];
                zx1 = Zx[zb + 256];
                zx2 = Zx[zb + 512];
                zx3 = Zx[zb + 768];
            }
            creg = sigf(z1)*creg + sigf(z0)*tanhf(z2);
            float hvv = sigf(z3)*tanhf(creg);
            unsigned hb = (__float_as_uint(hvv) & ~7u) | tag;
            float hm = __uint_as_float(hb);
            __hip_atomic_store(&hglob[(size_t)buf*16384 + (size_t)row*256 + p*32 + gd],
                               hm, __ATOMIC_RELAXED, __HIP_MEMORY_SCOPE_AGENT);
            out[((size_t)row*SS + s)*HH + p*32 + gd] = hvv;
            hs[gr][p*32 + gd] = (_Float16)hm;
        } else {
            unsigned long long* base = hgl64 + (size_t)buf*8192 + (size_t)g*1024;
            unsigned long long va = __hip_atomic_load(&base[oa], __ATOMIC_RELAXED, __HIP_MEMORY_SCOPE_AGENT);
            unsigned long long vb = __hip_atomic_load(&base[ob], __ATOMIC_RELAXED, __HIP_MEMORY_SCOPE_AGENT);
            unsigned long long vc = __hip_atomic_load(&base[oc], __ATOMIC_RELAXED, __HIP_MEMORY_SCOPE_AGENT);
            unsigned long long vd = 0;
            if (has4) vd = __hip_atomic_load(&base[od], __ATOMIC_RELAXED, __HIP_MEMORY_SCOPE_AGENT);
            bool da=false, db=false, dc=false, dd=!has4;
            while (!(da && db && dc && dd)){
                if (!da){
                    if ((((unsigned)va&7u)==tag) && (((unsigned)(va>>32)&7u)==tag)){
                        h2 t; t.x = (_Float16)__uint_as_float((unsigned)va);
                        t.y = (_Float16)__uint_as_float((unsigned)(va>>32));
                        hsu[oa] = __builtin_bit_cast(unsigned, t); da=true;
                    } else va = __hip_atomic_load(&base[oa], __ATOMIC_RELAXED, __HIP_MEMORY_SCOPE_AGENT);
                }
                if (!db){
                    if ((((unsigned)vb&7u)==tag) && (((unsigned)(vb>>32)&7u)==tag)){
                        h2 t; t.x = (_Float16)__uint_as_float((unsigned)vb);
                        t.y = (_Float16)__uint_as_float((unsigned)(vb>>32));
                        hsu[ob] = __builtin_bit_cast(unsigned, t); db=true;
                    } else vb = __hip_atomic_load(&base[ob], __ATOMIC_RELAXED, __HIP_MEMORY_SCOPE_AGENT);
                }
                if (!dc){
                    if ((((unsigned)vc&7u)==tag) && (((unsigned)(vc>>32)&7u)==tag)){
                        h2 t; t.x = (_Float16)__uint_as_float((unsigned)vc);
                        t.y = (_Float16)__uint_as_float((unsigned)(vc>>32));
                        hsu[oc] = __builtin_bit_cast(unsigned, t); dc=true;
                    } else vc = __hip_atomic_load(&base[oc], __ATOMIC_RELAXED, __HIP_MEMORY_SCOPE_AGENT);
                }
                if (!dd){
                    if ((((unsigned)vd&7u)==tag) && (((unsigned)(vd>>32)&7u)==tag)){
                        h2 t; t.x = (_Float16)__uint_as_float((unsigned)vd);
                        t.y = (_Float16)__uint_as_float((unsigned)(vd>>32));
                        hsu[od] = __builtin_bit_cast(unsigned, t); dd=true;
                    } else vd = __hip_atomic_load(&base[od], __ATOMIC_RELAXED, __HIP_MEMORY_SCOPE_AGENT);
                }
            }
        }
        asm volatile("s_waitcnt lgkmcnt(0)" ::: "memory");
        __builtin_amdgcn_s_barrier();                       // B: hs(s+1) complete
        asm volatile("" ::: "memory");
    }
}

// -------------------- attention: one block per (b, head), flash-style ----
__global__ __launch_bounds__(256) void attn_kernel(
    const float* __restrict__ qkv, const int* __restrict__ lengths, float* __restrict__ ctx)
{
    int bh = blockIdx.x; int b = bh >> 3, h = bh & 7;
    int len = lengths[b];
    int tid = threadIdx.x;
    __shared__ float Ks[512][32];
    __shared__ float Vs[512][32];
    for (int i = tid; i < len*32; i += 256){
        int s = i >> 5, d = i & 31;
        size_t base = ((size_t)b*512 + s)*768 + h*32 + d;
        Ks[s][d] = qkv[base + 256];
        Vs[s][d] = qkv[base + 512];
    }
    __syncthreads();
    const float rs = 0.1767766952966369f;   // 1/sqrt(32)
    for (int q0 = 0; q0 < 512; q0 += 256){
        int q = q0 + tid;
        if (q >= len) continue;
        float qr[32];
        size_t qb = ((size_t)b*512 + q)*768 + h*32;
        #pragma unroll
        for (int d=0; d<32; d+=4){
            float4 t4 = *(const float4*)&qkv[qb+d];
            qr[d]=t4.x; qr[d+1]=t4.y; qr[d+2]=t4.z; qr[d+3]=t4.w;
        }
        float m = -3.4e38f, l = 0.f, acc[32];
        #pragma unroll
        for (int d=0;d<32;d++) acc[d]=0.f;
        for (int k=0;k<len;k++){
            float sc = 0.f;
            #pragma unroll
            for (int d=0;d<32;d+=4){
                float4 kv = *(const float4*)&Ks[k][d];
                sc += qr[d]*kv.x + qr[d+1]*kv.y + qr[d+2]*kv.z + qr[d+3]*kv.w;
            }
            sc *= rs;
            float nm = fmaxf(m, sc);
            float f  = expf(m - nm);
            float pc = expf(sc - nm);
            l = l*f + pc;
            #pragma unroll
            for (int d=0;d<32;d+=4){
                float4 vv = *(const float4*)&Vs[k][d];
                acc[d]   = acc[d]*f   + pc*vv.x;
                acc[d+1] = acc[d+1]*f + pc*vv.y;
                acc[d+2] = acc[d+2]*f + pc*vv.z;
                acc[d+3] = acc[d+3]*f + pc*vv.w;
            }
            m = nm;
        }
        float inv = 1.f/l;
        size_t cb = ((size_t)b*512 + q)*256 + h*32;
        #pragma unroll
        for (int d=0;d<32;d+=4){
            float4 o; o.x=acc[d]*inv; o.y=acc[d+1]*inv; o.z=acc[d+2]*inv; o.w=acc[d+3]*inv;
            *(float4*)&ctx[cb+d] = o;
        }
    }
}

// -------------------- MoE routing: argmax expert + gate + bucket ----------
__global__ __launch_bounds__(256) void route_kernel(
    const float* __restrict__ src, const float* __restrict__ rw,
    const int* __restrict__ lengths, unsigned* __restrict__ cnt,
    int* __restrict__ bucket, float* __restrict__ gates)
{
    int tok = blockIdx.x*256 + threadIdx.x;
    int b = tok >> 9, t = tok & 511;
    if (t >= lengths[b]) return;
    const float* s = src + (size_t)tok*256;
    float l0=0.f,l1=0.f,l2=0.f,l3=0.f,l4=0.f;
    for (int d=0; d<256; ++d){
        float v = s[d];
        const float* r = &rw[d*5];
        l0 = fmaf(v, r[0], l0);
        l1 = fmaf(v, r[1], l1);
        l2 = fmaf(v, r[2], l2);
        l3 = fmaf(v, r[3], l3);
        l4 = fmaf(v, r[4], l4);
    }
    float mx = l0; int ix = 0;
    if (l1 > mx){ mx=l1; ix=1; }
    if (l2 > mx){ mx=l2; ix=2; }
    if (l3 > mx){ mx=l3; ix=3; }
    if (l4 > mx){ mx=l4; ix=4; }
    float ssum = expf(l0-mx)+expf(l1-mx)+expf(l2-mx)+expf(l3-mx)+expf(l4-mx);
    int slot = (int)atomicAdd(&cnt[ix], 1u);
    bucket[ix*32768 + slot] = tok;
    gates[tok] = 1.0f/ssum;
}

// -------------------- MoE expert-batched GEMM + gate + residual + LN2 -----
// grid (512 chunks, 5 experts), 64 tokens per block, 256 threads (8x32 tile:
// thread = 8 tokens x 8 dims). Expert weights stream from L2 (2.5MB/XCD hot).
__global__ __launch_bounds__(256) void moe_gemm(
    const float* __restrict__ src, const int* __restrict__ bucket,
    const unsigned* __restrict__ cnt, const float* __restrict__ gates,
    const float* __restrict__ w1, const float* __restrict__ b1,
    const float* __restrict__ w2, const float* __restrict__ b2,
    const float* __restrict__ g2, const float* __restrict__ bt2,
    float* __restrict__ out)
{
    int e = blockIdx.y;
    int count = (int)cnt[e];
    int start = blockIdx.x*64;
    if (start >= count) return;
    int n = min(64, count-start);
    __shared__ float sv[64][256];
    __shared__ float hv[64][256];
    __shared__ int   toks[64];
    __shared__ float gts[64];
    int tid = threadIdx.x;
    if (tid < 64){
        int idx = start + min(tid, n-1);
        int tk = bucket[e*32768 + idx];
        toks[tid] = tk;
        gts[tid]  = gates[tk];
    }
    __syncthreads();
    for (int i=0;i<64;i++)
        sv[i][tid] = src[(size_t)toks[i]*256 + tid];
    __syncthreads();
    int tt = tid >> 5, dd = tid & 31;
    const float* W1 = w1 + (size_t)e*65536;
    const float* W2 = w2 + (size_t)e*65536;
    float acc[8][8];
    {
        float4 bA = *(const float4*)&b1[e*256 + dd*8];
        float4 bB = *(const float4*)&b1[e*256 + dd*8 + 4];
        #pragma unroll
        for (int i=0;i<8;i++){
            acc[i][0]=bA.x; acc[i][1]=bA.y; acc[i][2]=bA.z; acc[i][3]=bA.w;
            acc[i][4]=bB.x; acc[i][5]=bB.y; acc[i][6]=bB.z; acc[i][7]=bB.w;
        }
    }
    #pragma unroll 2
    for (int k=0;k<256;k++){
        float4 wA = *(const float4*)&W1[(size_t)k*256 + dd*8];
        float4 wB = *(const float4*)&W1[(size_t)k*256 + dd*8 + 4];
        float wv0=wA.x,wv1=wA.y,wv2=wA.z,wv3=wA.w,wv4=wB.x,wv5=wB.y,wv6=wB.z,wv7=wB.w;
        #pragma unroll
        for (int i=0;i<8;i++){
            float hvv = sv[tt*8+i][k];
            acc[i][0]=fmaf(hvv,wv0,acc[i][0]); acc[i][1]=fmaf(hvv,wv1,acc[i][1]);
            acc[i][2]=fmaf(hvv,wv2,acc[i][2]); acc[i][3]=fmaf(hvv,wv3,acc[i][3]);
            acc[i][4]=fmaf(hvv,wv4,acc[i][4]); acc[i][5]=fmaf(hvv,wv5,acc[i][5]);
            acc[i][6]=fmaf(hvv,wv6,acc[i][6]); acc[i][7]=fmaf(hvv,wv7,acc[i][7]);
        }
    }
    #pragma unroll
    for (int i=0;i<8;i++){
        #pragma unroll
        for (int j=0;j<8;j++) hv[tt*8+i][dd*8+j] = fmaxf(acc[i][j], 0.f);
    }
    __syncthreads();
    // GEMM2
    {
        float4 bA = *(const float4*)&b2[e*256 + dd*8];
        float4 bB = *(const float4*)&b2[e*256 + dd*8 + 4];
        #pragma unroll
        for (int i=0;i<8;i++){
            acc[i][0]=bA.x; acc[i][1]=bA.y; acc[i][2]=bA.z; acc[i][3]=bA.w;
            acc[i][4]=bB.x; acc[i][5]=bB.y; acc[i][6]=bB.z; acc[i][7]=bB.w;
        }
    }
    #pragma unroll 2
    for (int k=0;k<256;k++){
        float4 wA = *(const float4*)&W2[(size_t)k*256 + dd*8];
        float4 wB = *(const float4*)&W2[(size_t)k*256 + dd*8 + 4];
        float wv0=wA.x,wv1=wA.y,wv2=wA.z,wv3=wA.w,wv4=wB.x,wv5=wB.y,wv6=wB.z,wv7=wB.w;
        #pragma unroll
        for (int i=0;i<8;i++){
            float hvv = hv[tt*8+i][k];
            acc[i][0]=fmaf(hvv,wv0,acc[i][0]); acc[i][1]=fmaf(hvv,wv1,acc[i][1]);
            acc[i][2]=fmaf(hvv,wv2,acc[i][2]); acc[i][3]=fmaf(hvv,wv3,acc[i][3]);
            acc[i][4]=fmaf(hvv,wv4,acc[i][4]); acc[i][5]=fmaf(hvv,wv5,acc[i][5]);
            acc[i][6]=fmaf(hvv,wv6,acc[i][6]); acc[i][7]=fmaf(hvv,wv7,acc[i][7]);
        }
    }
    // r = src + gate*y, then LN2 per token
    float4 gA = *(const float4*)&g2[dd*8];
    float4 gB = *(const float4*)&g2[dd*8 + 4];
    float4 tA = *(const float4*)&bt2[dd*8];
    float4 tB = *(const float4*)&bt2[dd*8 + 4];
    float gv[8] = {gA.x,gA.y,gA.z,gA.w,gB.x,gB.y,gB.z,gB.w};
    float tv[8] = {tA.x,tA.y,tA.z,tA.w,tB.x,tB.y,tB.z,tB.w};
    #pragma unroll
    for (int i=0;i<8;i++){
        float gate = gts[tt*8+i];
        float4 sA = *(const float4*)&sv[tt*8+i][dd*8];
        float4 sB = *(const float4*)&sv[tt*8+i][dd*8 + 4];
        float svv[8] = {sA.x,sA.y,sA.z,sA.w,sB.x,sB.y,sB.z,sB.w};
        float s = 0.f, q = 0.f;
        #pragma unroll
        for (int j=0;j<8;j++){
            float r = svv[j] + gate*acc[i][j];
            acc[i][j] = r;
            s += r; q += r*r;
        }
        #pragma unroll
        for (int m=16;m>=1;m>>=1){ s += __shfl_xor(s,m); q += __shfl_xor(q,m); }
        float mean = s*(1.f/256.f), var = q*(1.f/256.f)-mean*mean;
        float rstd = rsqrtf(var + 1e-5f);
        if (tt*8+i < n){
            int tok = toks[tt*8+i];
            float o[8];
            #pragma unroll
            for (int j=0;j<8;j++) o[j] = (acc[i][j]-mean)*rstd*gv[j] + tv[j];
            float4 oA = make_float4(o[0],o[1],o[2],o[3]);
            float4 oB = make_float4(o[4],o[5],o[6],o[7]);
            *(float4*)&out[(size_t)tok*256 + dd*8]     = oA;
            *(float4*)&out[(size_t)tok*256 + dd*8 + 4] = oB;
        }
    }
}

// -------------------- masked mean pool ------------------------------------
__global__ __launch_bounds__(256) void pool_kernel(
    const float* __restrict__ out2, const int* __restrict__ lengths, float* __restrict__ pooled)
{
    int b = blockIdx.x, d = threadIdx.x;
    int len = lengths[b];
    float s = 0.f;
    for (int t=0;t<len;t++) s += out2[((size_t)b*512 + t)*256 + d];
    pooled[b*256 + d] = s / (float)len;
}

// -------------------- classifier head -------------------------------------
__global__ __launch_bounds__(256) void cls_kernel(
    const float* __restrict__ pooled, const float* __restrict__ w1,
    const float* __restrict__ b1, const float* __restrict__ lg, const float* __restrict__ lb,
    const float* __restrict__ w2, const float* __restrict__ b2, float* __restrict__ outp)
{
    int b = blockIdx.x, j = threadIdx.x;
    __shared__ float pv[256];
    __shared__ float red[8];
    pv[j] = pooled[b*256 + j];
    __syncthreads();
    float acc = b1[j];
    for (int d=0; d<256; d+=4){
        float4 p4 = *(const float4*)&pv[d];
        const float* wr = &w1[(size_t)j*256 + d];
        acc += p4.x*wr[0] + p4.y*wr[1] + p4.z*wr[2] + p4.w*wr[3];
    }
    float s = acc, q = acc*acc;
    #pragma unroll
    for (int m=32;m>=1;m>>=1){ s += __shfl_xor(s,m); q += __shfl_xor(q,m); }
    int wid = j>>6;
    if ((j&63)==0){ red[wid]=s; red[4+wid]=q; }
    __syncthreads();
    s = red[0]+red[1]+red[2]+red[3]; q = red[4]+red[5]+red[6]+red[7];
    float mean = s*(1.f/256.f), var = q*(1.f/256.f)-mean*mean, rstd = rsqrtf(var+1e-5f);
    float h1v = fmaxf((acc-mean)*rstd*lg[j]+lb[j], 0.f);
    float pr = h1v * w2[j];
    __syncthreads();
    #pragma unroll
    for (int m=32;m>=1;m>>=1) pr += __shfl_xor(pr,m);
    if ((j&63)==0) red[wid] = pr;
    __syncthreads();
    if (j==0) outp[b] = red[0]+red[1]+red[2]+red[3] + b2[0];
}

// ==========================================================================
extern "C" void kernel_launch(void* const* d_in, const int* in_sizes, int n_in,
                              void* d_out, int out_size, void* d_ws, size_t ws_size,
                              hipStream_t stream)
{
    const float* x       = (const float*)d_in[0];
    const int*   lengths = (const int*)  d_in[1];
    const float* fe_w    = (const float*)d_in[2];
    const float* fe_b    = (const float*)d_in[3];
    const float* fe_ln_g = (const float*)d_in[4];
    const float* fe_ln_b = (const float*)d_in[5];
    const float* w_ih    = (const float*)d_in[6];
    const float* w_hh    = (const float*)d_in[7];
    const float* b_ih    = (const float*)d_in[8];
    const float* b_hh    = (const float*)d_in[9];
    const float* attn_w  = (const float*)d_in[10];
    const float* attn_b  = (const float*)d_in[11];
    const float* attn_ow = (const float*)d_in[12];
    const float* attn_ob = (const float*)d_in[13];
    const float* ln1_g   = (const float*)d_in[14];
    const float* ln1_b   = (const float*)d_in[15];
    const float* router_w= (const float*)d_in[16];
    const float* e_w1    = (const float*)d_in[17];
    const float* e_b1    = (const float*)d_in[18];
    const float* e_w2    = (const float*)d_in[19];
    const float* e_b2    = (const float*)d_in[20];
    const float* ln2_g   = (const float*)d_in[21];
    const float* ln2_b   = (const float*)d_in[22];
    const float* cl_w1   = (const float*)d_in[23];
    const float* cl_b1   = (const float*)d_in[24];
    const float* cl_ln_g = (const float*)d_in[25];
    const float* cl_ln_b = (const float*)d_in[26];
    const float* cl_w2   = (const float*)d_in[27];
    const float* cl_b2   = (const float*)d_in[28];
    float* outp = (float*)d_out;

    // workspace layout (floats)
    const size_t NEED = (size_t)50381832 * 4;
    if (ws_size < NEED){
        fprintf(stderr, "kernel_launch: ws too small (%zu < %zu)\n", ws_size, NEED);
        return;
    }
    float* W     = (float*)d_ws;
    float* h0    = W;                    // [T,256]   32MB
    float* Zx    = W + 8388608;          // [T,1024] 128MB
    float* lstm  = W + 41943040;         // [T,256]   32MB
    float* hglob = W + 50331648;         // [2,64,256]
    float* pooled= W + 50364416;         // [64,256]
    float* bcomb = W + 50380800;         // [1024]
    // aliases into dead regions
    float* qkv  = Zx;                    // [T,768] (after LSTM consumes Zx)
    float* ctx  = Zx + 25165824;         // [T,256]
    float* aop  = h0;                    // [T,256] (h0 dead after Zx GEMM)
    float* src  = lstm;                  // LN1 in-place
    float* out2 = Zx;                    // [T,256] (qkv/ctx dead)
    // MoE scratch aliases (h0 region dead after ln1 consumes aop)
    float*    gates  = h0;               // [32768]
    int*      bucket = (int*)(h0 + 32768);       // [5*32768]
    unsigned* cnt    = (unsigned*)pooled;        // [8] (pooled later overwritten)

    prep_kernel<<<dim3(128), 256, 0, stream>>>(b_ih, b_hh, bcomb, hglob, cnt);
    // feature extractor GEMM + LN + ReLU
    gemm_nt<<<dim3(4,512), 256, 0, stream>>>(x, fe_w, fe_b, h0, 256, lengths);
    ln_act<<<dim3(32768), 256, 0, stream>>>(h0, nullptr, fe_ln_g, fe_ln_b, lengths, 1);
    // LSTM input projection for all timesteps
    gemm_nt<<<dim3(16,512), 256, 0, stream>>>(h0, w_ih, bcomb, Zx, 1024, lengths);
    // recurrent LSTM
    lstm_kernel<<<dim3(64), 512, 0, stream>>>(Zx, w_hh, lengths, hglob, lstm);
    // attention
    gemm_nt<<<dim3(12,512), 256, 0, stream>>>(lstm, attn_w, attn_b, qkv, 768, lengths);
    attn_kernel<<<dim3(512), 256, 0, stream>>>(qkv, lengths, ctx);
    gemm_nt<<<dim3(4,512), 256, 0, stream>>>(ctx, attn_ow, attn_ob, aop, 256, lengths);
    // post-norm residual LN1 (in-place into lstm -> src)
    ln_act<<<dim3(32768), 256, 0, stream>>>(src, aop, ln1_g, ln1_b, lengths, 0);
    // MoE: route then expert-batched GEMM (+gate+residual+LN2)
    route_kernel<<<dim3(128), 256, 0, stream>>>(src, router_w, lengths, cnt, bucket, gates);
    moe_gemm<<<dim3(512,5), 256, 0, stream>>>(src, bucket, cnt, gates,
                                              e_w1, e_b1, e_w2, e_b2, ln2_g, ln2_b, out2);
    // masked mean pool + classifier
    pool_kernel<<<dim3(64), 256, 0, stream>>>(out2, lengths, pooled);
    cls_kernel<<<dim3(64), 256, 0, stream>>>(pooled, cl_w1, cl_b1, cl_ln_g, cl_ln_b,
                                             cl_w2, cl_b2, outp);
}

// Round 6
// 2017.879 us; speedup vs baseline: 1.8734x; 1.6111x over previous
//
#include <hip/hip_runtime.h>
#include <cstdio>
#include <math.h>

// Problem constants
#define BB 64
#define SS 512
#define HH 256
#define G4 1024   // 4*H
#define TT (BB*SS)  // 32768

typedef _Float16 h2 __attribute__((ext_vector_type(2)));
typedef _Float16 h8 __attribute__((ext_vector_type(8)));
typedef float f4v __attribute__((ext_vector_type(4)));

__device__ __forceinline__ float sigf(float x){ return 1.0f/(1.0f+expf(-x)); }

// -------------------- prep: combined LSTM bias + zero h exchange + cnt -----
__global__ void prep_kernel(const float* __restrict__ b_ih, const float* __restrict__ b_hh,
                            float* __restrict__ bcomb, float* __restrict__ hglob,
                            unsigned* __restrict__ cnt){
    int i = blockIdx.x*blockDim.x + threadIdx.x;
    if (i < G4) bcomb[i] = b_ih[i] + b_hh[i];
    if (i < 8)  cnt[i] = 0u;
    hglob[i] = 0.f;                       // 128 blocks x 256 = 32768 = 2*64*2*128
}

// -------------------- fp16 MFMA GEMM: C[M,N] = A[M,K] * B[N,K]^T + bias ----
// K=256 fixed. 128x128 tile, 256 threads = 4 waves (2x2 quadrants), BK=32.
// A,B fp32 in global, converted to fp16 during LDS staging; fp32 accum.
__global__ __launch_bounds__(256) void gemm_mfma(
    const float* __restrict__ A, const float* __restrict__ Bw,
    const float* __restrict__ bias, float* __restrict__ C,
    int N, const int* __restrict__ lengths)
{
    int m0 = blockIdx.y * 128, n0 = blockIdx.x * 128;
    if (lengths){ int b = m0 >> 9, t0 = m0 & 511; if (t0 >= lengths[b]) return; }
    __shared__ _Float16 Asd[128][40];
    __shared__ _Float16 Bsd[128][40];
    int tid = threadIdx.x;
    int wave = tid >> 6, lane = tid & 63;
    int wr = (wave >> 1) * 64, wc = (wave & 1) * 64;
    int fr = lane & 15, fk = (lane >> 4) * 8;
    int srow = tid >> 1, skh = (tid & 1) * 16;
    const float* gA = A  + (size_t)(m0 + srow)*256 + skh;
    const float* gB = Bw + (size_t)(n0 + srow)*256 + skh;
    f4v acc[4][4];
    #pragma unroll
    for (int i=0;i<4;i++)
        #pragma unroll
        for (int j=0;j<4;j++) acc[i][j] = (f4v){0.f,0.f,0.f,0.f};

    for (int kt = 0; kt < 8; ++kt){
        int k0 = kt*32;
        float4 a0 = *(const float4*)(gA + k0);
        float4 a1 = *(const float4*)(gA + k0 + 4);
        float4 a2 = *(const float4*)(gA + k0 + 8);
        float4 a3 = *(const float4*)(gA + k0 + 12);
        float4 b0 = *(const float4*)(gB + k0);
        float4 b1 = *(const float4*)(gB + k0 + 4);
        float4 b2 = *(const float4*)(gB + k0 + 8);
        float4 b3 = *(const float4*)(gB + k0 + 12);
        __syncthreads();   // previous iter's frag reads complete
        {
            _Float16* da = &Asd[srow][skh];
            h2 t;
            t.x=(_Float16)a0.x; t.y=(_Float16)a0.y; *(h2*)(da+0)=t;
            t.x=(_Float16)a0.z; t.y=(_Float16)a0.w; *(h2*)(da+2)=t;
            t.x=(_Float16)a1.x; t.y=(_Float16)a1.y; *(h2*)(da+4)=t;
            t.x=(_Float16)a1.z; t.y=(_Float16)a1.w; *(h2*)(da+6)=t;
            t.x=(_Float16)a2.x; t.y=(_Float16)a2.y; *(h2*)(da+8)=t;
            t.x=(_Float16)a2.z; t.y=(_Float16)a2.w; *(h2*)(da+10)=t;
            t.x=(_Float16)a3.x; t.y=(_Float16)a3.y; *(h2*)(da+12)=t;
            t.x=(_Float16)a3.z; t.y=(_Float16)a3.w; *(h2*)(da+14)=t;
            _Float16* db = &Bsd[srow][skh];
            t.x=(_Float16)b0.x; t.y=(_Float16)b0.y; *(h2*)(db+0)=t;
            t.x=(_Float16)b0.z; t.y=(_Float16)b0.w; *(h2*)(db+2)=t;
            t.x=(_Float16)b1.x; t.y=(_Float16)b1.y; *(h2*)(db+4)=t;
            t.x=(_Float16)b1.z; t.y=(_Float16)b1.w; *(h2*)(db+6)=t;
            t.x=(_Float16)b2.x; t.y=(_Float16)b2.y; *(h2*)(db+8)=t;
            t.x=(_Float16)b2.z; t.y=(_Float16)b2.w; *(h2*)(db+10)=t;
            t.x=(_Float16)b3.x; t.y=(_Float16)b3.y; *(h2*)(db+12)=t;
            t.x=(_Float16)b3.z; t.y=(_Float16)b3.w; *(h2*)(db+14)=t;
        }
        __syncthreads();   // stage complete
        h8 af[4], bf[4];
        #pragma unroll
        for (int mt=0;mt<4;mt++) af[mt] = *(const h8*)&Asd[wr + mt*16 + fr][fk];
        #pragma unroll
        for (int nt=0;nt<4;nt++) bf[nt] = *(const h8*)&Bsd[wc + nt*16 + fr][fk];
        #pragma unroll
        for (int mt=0;mt<4;mt++)
            #pragma unroll
            for (int nt=0;nt<4;nt++)
                acc[mt][nt] = __builtin_amdgcn_mfma_f32_16x16x32_f16(af[mt], bf[nt], acc[mt][nt], 0,0,0);
    }
    // epilogue: row = m0+wr+mt*16+(lane>>4)*4+j, col = n0+wc+nt*16+(lane&15)
    int rbase = m0 + wr + (lane>>4)*4;
    #pragma unroll
    for (int nt=0;nt<4;nt++){
        int col = n0 + wc + nt*16 + fr;
        float bv = bias ? bias[col] : 0.f;
        #pragma unroll
        for (int mt=0;mt<4;mt++){
            int row = rbase + mt*16;
            #pragma unroll
            for (int j=0;j<4;j++)
                C[(size_t)(row+j)*N + col] = acc[mt][nt][j] + bv;
        }
    }
}

// -------------------- per-row LayerNorm (optional residual add, optional ReLU)
__global__ __launch_bounds__(256) void ln_act(
    float* __restrict__ X, const float* __restrict__ add,
    const float* __restrict__ gg, const float* __restrict__ bb,
    const int* __restrict__ lengths, int relu)
{
    int row = blockIdx.x;
    { int b = row >> 9, t = row & 511; if (t >= lengths[b]) return; }
    int tid = threadIdx.x;
    __shared__ float red[8];
    size_t idx = (size_t)row*HH + tid;
    float v = X[idx];
    if (add) v += add[idx];
    float s = v, q = v*v;
    #pragma unroll
    for (int m=32;m>=1;m>>=1){ s += __shfl_xor(s,m); q += __shfl_xor(q,m); }
    if ((tid&63)==0){ red[tid>>6]=s; red[4+(tid>>6)]=q; }
    __syncthreads();
    s = red[0]+red[1]+red[2]+red[3]; q = red[4]+red[5]+red[6]+red[7];
    float mean = s*(1.f/HH);
    float var  = q*(1.f/HH) - mean*mean;
    float rstd = rsqrtf(var + 1e-5f);
    float o = (v-mean)*rstd*gg[tid] + bb[tid];
    if (relu) o = fmaxf(o, 0.f);
    X[idx] = o;
}

// -------------------- LSTM: 128 blocks = 64 rows x 2 hidden-partitions ----
// Block (row, p): owns dims [p*128, p*128+128) of batch row `row`. W slice
// (4 gates x 128 dims x 256 k, fp16) lives in VGPRs (128/thread, 512 thr).
// Per step: poll load issued early -> z over own k-half -> spin+land remote
// -> barrier -> z over remote k-half -> zfull LDS -> 128 gate threads.
// Exchange: fp32 with 3-LSB mantissa tag, relaxed agent (sc1) atomics.
__global__ __launch_bounds__(512) void lstm_kernel(
    const float* __restrict__ Zx, const float* __restrict__ whh,
    const int* __restrict__ lengths, float* __restrict__ hglob,
    float* __restrict__ out)
{
    int bid = blockIdx.x;
    int row = bid >> 1, p = bid & 1;
    int tid = threadIdx.x;
    __shared__ __align__(16) _Float16 hs_own[128];
    __shared__ __align__(16) _Float16 hs_rem[128];
    __shared__ float zfull[512];

    // this thread owns z column j = tid = q*128 + d
    int q = tid >> 7, d = tid & 127;
    const float* wrow = whh + (size_t)(q*256 + p*128 + d)*256;
    const float* wown = wrow + p*128;
    const float* wrem = wrow + (1-p)*128;
    h2 wA[64], wB[64];
    #pragma unroll
    for (int c=0;c<32;c++){
        float4 w4 = *(const float4*)(wown + c*4);
        h2 a; a.x=(_Float16)w4.x; a.y=(_Float16)w4.y;
        h2 b; b.x=(_Float16)w4.z; b.y=(_Float16)w4.w;
        wA[2*c]=a; wA[2*c+1]=b;
    }
    #pragma unroll
    for (int c=0;c<32;c++){
        float4 w4 = *(const float4*)(wrem + c*4);
        h2 a; a.x=(_Float16)w4.x; a.y=(_Float16)w4.y;
        h2 b; b.x=(_Float16)w4.z; b.y=(_Float16)w4.w;
        wB[2*c]=a; wB[2*c+1]=b;
    }
    int Tg = lengths[row];
    float creg = 0.f;

    if (tid < 64) ((unsigned*)hs_own)[tid] = 0u;
    else if (tid < 128) ((unsigned*)hs_rem)[tid-64] = 0u;
    __syncthreads();

    // Zx prefetch for gate threads (tid<128 handles dim d_g = tid)
    float zx0=0.f, zx1=0.f, zx2=0.f, zx3=0.f;
    size_t zbase = (size_t)row*SS*G4 + (size_t)(p*128 + tid);
    if (tid < 128 && Tg > 0){
        zx0 = Zx[zbase      ];
        zx1 = Zx[zbase + 256];
        zx2 = Zx[zbase + 512];
        zx3 = Zx[zbase + 768];
    }

    unsigned long long* hgl64 = (unsigned long long*)hglob;
    union U16 { float4 f; h2 h[4]; };

    for (int s = 0; s < Tg; ++s){
        bool pollme = (tid < 64) && (s > 0);
        unsigned tagP = ((unsigned)s & 7u) ^ 5u;
        size_t paddr = ((size_t)((s&1)*64 + row)*2 + (1-p))*64 + tid;
        unsigned long long pv = 0;
        if (pollme) pv = __hip_atomic_load(&hgl64[paddr], __ATOMIC_RELAXED, __HIP_MEMORY_SCOPE_AGENT);

        // z over own k-half (hs_own written locally last step)
        float accA = 0.f, accB = 0.f;
        #pragma unroll
        for (int c=0;c<16;c++){
            U16 u; u.f = *(const float4*)&hs_own[c*8];
            accA = __builtin_amdgcn_fdot2(u.h[0], wA[c*4+0], accA, false);
            accB = __builtin_amdgcn_fdot2(u.h[1], wA[c*4+1], accB, false);
            accA = __builtin_amdgcn_fdot2(u.h[2], wA[c*4+2], accA, false);
            accB = __builtin_amdgcn_fdot2(u.h[3], wA[c*4+3], accB, false);
        }
        if (pollme){
            while ((((unsigned)pv & 7u) != tagP) || (((unsigned)(pv>>32) & 7u) != tagP))
                pv = __hip_atomic_load(&hgl64[paddr], __ATOMIC_RELAXED, __HIP_MEMORY_SCOPE_AGENT);
            h2 t; t.x = (_Float16)__uint_as_float((unsigned)pv);
            t.y = (_Float16)__uint_as_float((unsigned)(pv>>32));
            ((h2*)hs_rem)[tid] = t;
        }
        asm volatile("s_waitcnt lgkmcnt(0)" ::: "memory");
        __builtin_amdgcn_s_barrier();            // D: hs_rem complete
        asm volatile("" ::: "memory");

        // z over remote k-half
        #pragma unroll
        for (int c=0;c<16;c++){
            U16 u; u.f = *(const float4*)&hs_rem[c*8];
            accA = __builtin_amdgcn_fdot2(u.h[0], wB[c*4+0], accA, false);
            accB = __builtin_amdgcn_fdot2(u.h[1], wB[c*4+1], accB, false);
            accA = __builtin_amdgcn_fdot2(u.h[2], wB[c*4+2], accA, false);
            accB = __builtin_amdgcn_fdot2(u.h[3], wB[c*4+3], accB, false);
        }
        zfull[tid] = accA + accB;
        asm volatile("s_waitcnt lgkmcnt(0)" ::: "memory");
        __builtin_amdgcn_s_barrier();            // E: zfull ready
        asm volatile("" ::: "memory");

        if (tid < 128){
            float z0 = zfull[tid      ] + zx0;
            float z1 = zfull[128 + tid] + zx1;
            float z2 = zfull[256 + tid] + zx2;
            float z3 = zfull[384 + tid] + zx3;
            if (s+1 < Tg){
                size_t zb = zbase + (size_t)(s+1)*G4;
                zx0 = Zx[zb      ];
                zx1 = Zx[zb + 256];
                zx2 = Zx[zb + 512];
                zx3 = Zx[zb + 768];
            }
            creg = sigf(z1)*creg + sigf(z0)*tanhf(z2);
            float hvv = sigf(z3)*tanhf(creg);
            int buf2 = (s+1) & 1;
            unsigned tag2 = (((unsigned)(s+1)) & 7u) ^ 5u;
            unsigned hb = (__float_as_uint(hvv) & ~7u) | tag2;
            float hm = __uint_as_float(hb);
            __hip_atomic_store(&hglob[((size_t)(buf2*64 + row)*2 + p)*128 + tid],
                               hm, __ATOMIC_RELAXED, __HIP_MEMORY_SCOPE_AGENT);
            out[((size_t)row*SS + s)*HH + p*128 + tid] = hvv;
            hs_own[tid] = (_Float16)hm;
        }
        asm volatile("s_waitcnt lgkmcnt(0)" ::: "memory");
        __builtin_amdgcn_s_barrier();            // F: hs_own ready
        asm volatile("" ::: "memory");
    }
}

// -------------------- attention: one block per (b, head), flash-style ----
__global__ __launch_bounds__(256) void attn_kernel(
    const float* __restrict__ qkv, const int* __restrict__ lengths, float* __restrict__ ctx)
{
    int bh = blockIdx.x; int b = bh >> 3, h = bh & 7;
    int len = lengths[b];
    int tid = threadIdx.x;
    __shared__ float Ks[512][32];
    __shared__ float Vs[512][32];
    for (int i = tid; i < len*32; i += 256){
        int s = i >> 5, d = i & 31;
        size_t base = ((size_t)b*512 + s)*768 + h*32 + d;
        Ks[s][d] = qkv[base + 256];
        Vs[s][d] = qkv[base + 512];
    }
    __syncthreads();
    const float rs = 0.1767766952966369f;   // 1/sqrt(32)
    for (int q0 = 0; q0 < 512; q0 += 256){
        int q = q0 + tid;
        if (q >= len) continue;
        float qr[32];
        size_t qb = ((size_t)b*512 + q)*768 + h*32;
        #pragma unroll
        for (int d=0; d<32; d+=4){
            float4 t4 = *(const float4*)&qkv[qb+d];
            qr[d]=t4.x; qr[d+1]=t4.y; qr[d+2]=t4.z; qr[d+3]=t4.w;
        }
        float m = -3.4e38f, l = 0.f, acc[32];
        #pragma unroll
        for (int d=0;d<32;d++) acc[d]=0.f;
        for (int k=0;k<len;k++){
            float sc = 0.f;
            #pragma unroll
            for (int d=0;d<32;d+=4){
                float4 kv = *(const float4*)&Ks[k][d];
                sc += qr[d]*kv.x + qr[d+1]*kv.y + qr[d+2]*kv.z + qr[d+3]*kv.w;
            }
            sc *= rs;
            float nm = fmaxf(m, sc);
            float f  = expf(m - nm);
            float pc = expf(sc - nm);
            l = l*f + pc;
            #pragma unroll
            for (int d=0;d<32;d+=4){
                float4 vv = *(const float4*)&Vs[k][d];
                acc[d]   = acc[d]*f   + pc*vv.x;
                acc[d+1] = acc[d+1]*f + pc*vv.y;
                acc[d+2] = acc[d+2]*f + pc*vv.z;
                acc[d+3] = acc[d+3]*f + pc*vv.w;
            }
            m = nm;
        }
        float inv = 1.f/l;
        size_t cb = ((size_t)b*512 + q)*256 + h*32;
        #pragma unroll
        for (int d=0;d<32;d+=4){
            float4 o; o.x=acc[d]*inv; o.y=acc[d+1]*inv; o.z=acc[d+2]*inv; o.w=acc[d+3]*inv;
            *(float4*)&ctx[cb+d] = o;
        }
    }
}

// -------------------- MoE routing: one wave per token (coalesced) ---------
__global__ __launch_bounds__(256) void route_kernel(
    const float* __restrict__ src, const float* __restrict__ rw,
    const int* __restrict__ lengths, unsigned* __restrict__ cnt,
    int* __restrict__ bucket, float* __restrict__ gates)
{
    int wv = threadIdx.x >> 6, lane = threadIdx.x & 63;
    int tok = blockIdx.x*4 + wv;
    int b = tok >> 9, t = tok & 511;
    if (t >= lengths[b]) return;
    float4 xv = *(const float4*)&src[(size_t)tok*256 + lane*4];
    float l0,l1,l2,l3,l4;
    {
        const float* r0 = &rw[(lane*4)*5];
        l0 = xv.x*r0[0] + xv.y*r0[5] + xv.z*r0[10] + xv.w*r0[15];
        l1 = xv.x*r0[1] + xv.y*r0[6] + xv.z*r0[11] + xv.w*r0[16];
        l2 = xv.x*r0[2] + xv.y*r0[7] + xv.z*r0[12] + xv.w*r0[17];
        l3 = xv.x*r0[3] + xv.y*r0[8] + xv.z*r0[13] + xv.w*r0[18];
        l4 = xv.x*r0[4] + xv.y*r0[9] + xv.z*r0[14] + xv.w*r0[19];
    }
    #pragma unroll
    for (int m=32;m>=1;m>>=1){
        l0 += __shfl_xor(l0,m); l1 += __shfl_xor(l1,m); l2 += __shfl_xor(l2,m);
        l3 += __shfl_xor(l3,m); l4 += __shfl_xor(l4,m);
    }
    if (lane == 0){
        float mx = l0; int ix = 0;
        if (l1 > mx){ mx=l1; ix=1; }
        if (l2 > mx){ mx=l2; ix=2; }
        if (l3 > mx){ mx=l3; ix=3; }
        if (l4 > mx){ mx=l4; ix=4; }
        float ssum = expf(l0-mx)+expf(l1-mx)+expf(l2-mx)+expf(l3-mx)+expf(l4-mx);
        int slot = (int)atomicAdd(&cnt[ix], 1u);
        bucket[ix*32768 + slot] = tok;
        gates[tok] = 1.0f/ssum;
    }
}

// -------------------- MoE expert-batched GEMM + gate + residual + LN2 -----
__global__ __launch_bounds__(256) void moe_gemm(
    const float* __restrict__ src, const int* __restrict__ bucket,
    const unsigned* __restrict__ cnt, const float* __restrict__ gates,
    const float* __restrict__ w1, const float* __restrict__ b1,
    const float* __restrict__ w2, const float* __restrict__ b2,
    const float* __restrict__ g2, const float* __restrict__ bt2,
    float* __restrict__ out)
{
    int e = blockIdx.y;
    int count = (int)cnt[e];
    int start = blockIdx.x*64;
    if (start >= count) return;
    int n = min(64, count-start);
    __shared__ float sv[64][256];
    __shared__ float hv[64][256];
    __shared__ int   toks[64];
    __shared__ float gts[64];
    int tid = threadIdx.x;
    if (tid < 64){
        int idx = start + min(tid, n-1);
        int tk = bucket[e*32768 + idx];
        toks[tid] = tk;
        gts[tid]  = gates[tk];
    }
    __syncthreads();
    for (int i=0;i<64;i++)
        sv[i][tid] = src[(size_t)toks[i]*256 + tid];
    __syncthreads();
    int tt = tid >> 5, dd = tid & 31;
    const float* W1 = w1 + (size_t)e*65536;
    const float* W2 = w2 + (size_t)e*65536;
    float acc[8][8];
    {
        float4 bA = *(const float4*)&b1[e*256 + dd*8];
        float4 bB = *(const float4*)&b1[e*256 + dd*8 + 4];
        #pragma unroll
        for (int i=0;i<8;i++){
            acc[i][0]=bA.x; acc[i][1]=bA.y; acc[i][2]=bA.z; acc[i][3]=bA.w;
            acc[i][4]=bB.x; acc[i][5]=bB.y; acc[i][6]=bB.z; acc[i][7]=bB.w;
        }
    }
    #pragma unroll 2
    for (int k=0;k<256;k++){
        float4 wA = *(const float4*)&W1[(size_t)k*256 + dd*8];
        float4 wB = *(const float4*)&W1[(size_t)k*256 + dd*8 + 4];
        float wv0=wA.x,wv1=wA.y,wv2=wA.z,wv3=wA.w,wv4=wB.x,wv5=wB.y,wv6=wB.z,wv7=wB.w;
        #pragma unroll
        for (int i=0;i<8;i++){
            float hvv = sv[tt*8+i][k];
            acc[i][0]=fmaf(hvv,wv0,acc[i][0]); acc[i][1]=fmaf(hvv,wv1,acc[i][1]);
            acc[i][2]=fmaf(hvv,wv2,acc[i][2]); acc[i][3]=fmaf(hvv,wv3,acc[i][3]);
            acc[i][4]=fmaf(hvv,wv4,acc[i][4]); acc[i][5]=fmaf(hvv,wv5,acc[i][5]);
            acc[i][6]=fmaf(hvv,wv6,acc[i][6]); acc[i][7]=fmaf(hvv,wv7,acc[i][7]);
        }
    }
    #pragma unroll
    for (int i=0;i<8;i++){
        #pragma unroll
        for (int j=0;j<8;j++) hv[tt*8+i][dd*8+j] = fmaxf(acc[i][j], 0.f);
    }
    __syncthreads();
    {
        float4 bA = *(const float4*)&b2[e*256 + dd*8];
        float4 bB = *(const float4*)&b2[e*256 + dd*8 + 4];
        #pragma unroll
        for (int i=0;i<8;i++){
            acc[i][0]=bA.x; acc[i][1]=bA.y; acc[i][2]=bA.z; acc[i][3]=bA.w;
            acc[i][4]=bB.x; acc[i][5]=bB.y; acc[i][6]=bB.z; acc[i][7]=bB.w;
        }
    }
    #pragma unroll 2
    for (int k=0;k<256;k++){
        float4 wA = *(const float4*)&W2[(size_t)k*256 + dd*8];
        float4 wB = *(const float4*)&W2[(size_t)k*256 + dd*8 + 4];
        float wv0=wA.x,wv1=wA.y,wv2=wA.z,wv3=wA.w,wv4=wB.x,wv5=wB.y,wv6=wB.z,wv7=wB.w;
        #pragma unroll
        for (int i=0;i<8;i++){
            float hvv = hv[tt*8+i][k];
            acc[i][0]=fmaf(hvv,wv0,acc[i][0]); acc[i][1]=fmaf(hvv,wv1,acc[i][1]);
            acc[i][2]=fmaf(hvv,wv2,acc[i][2]); acc[i][3]=fmaf(hvv,wv3,acc[i][3]);
            acc[i][4]=fmaf(hvv,wv4,acc[i][4]); acc[i][5]=fmaf(hvv,wv5,acc[i][5]);
            acc[i][6]=fmaf(hvv,wv6,acc[i][6]); acc[i][7]=fmaf(hvv,wv7,acc[i][7]);
        }
    }
    float4 gA = *(const float4*)&g2[dd*8];
    float4 gB = *(const float4*)&g2[dd*8 + 4];
    float4 tA = *(const float4*)&bt2[dd*8];
    float4 tB = *(const float4*)&bt2[dd*8 + 4];
    float gv[8] = {gA.x,gA.y,gA.z,gA.w,gB.x,gB.y,gB.z,gB.w};
    float tv[8] = {tA.x,tA.y,tA.z,tA.w,tB.x,tB.y,tB.z,tB.w};
    #pragma unroll
    for (int i=0;i<8;i++){
        float gate = gts[tt*8+i];
        float4 sA = *(const float4*)&sv[tt*8+i][dd*8];
        float4 sB = *(const float4*)&sv[tt*8+i][dd*8 + 4];
        float svv[8] = {sA.x,sA.y,sA.z,sA.w,sB.x,sB.y,sB.z,sB.w};
        float s = 0.f, q = 0.f;
        #pragma unroll
        for (int j=0;j<8;j++){
            float r = svv[j] + gate*acc[i][j];
            acc[i][j] = r;
            s += r; q += r*r;
        }
        #pragma unroll
        for (int m=16;m>=1;m>>=1){ s += __shfl_xor(s,m); q += __shfl_xor(q,m); }
        float mean = s*(1.f/256.f), var = q*(1.f/256.f)-mean*mean;
        float rstd = rsqrtf(var + 1e-5f);
        if (tt*8+i < n){
            int tok = toks[tt*8+i];
            float o[8];
            #pragma unroll
            for (int j=0;j<8;j++) o[j] = (acc[i][j]-mean)*rstd*gv[j] + tv[j];
            float4 oA = make_float4(o[0],o[1],o[2],o[3]);
            float4 oB = make_float4(o[4],o[5],o[6],o[7]);
            *(float4*)&out[(size_t)tok*256 + dd*8]     = oA;
            *(float4*)&out[(size_t)tok*256 + dd*8 + 4] = oB;
        }
    }
}

// -------------------- masked mean pool (1024 threads, 4-way t-split) ------
__global__ __launch_bounds__(1024) void pool_kernel(
    const float* __restrict__ out2, const int* __restrict__ lengths, float* __restrict__ pooled)
{
    int b = blockIdx.x;
    int d = threadIdx.x & 255, c = threadIdx.x >> 8;
    int len = lengths[b];
    __shared__ float part[4][256];
    float s = 0.f;
    for (int t=c; t<len; t+=4) s += out2[((size_t)b*512+t)*256 + d];
    part[c][d] = s;
    __syncthreads();
    if (c==0) pooled[b*256+d] = (part[0][d]+part[1][d]+part[2][d]+part[3][d]) / (float)len;
}

// -------------------- classifier head -------------------------------------
__global__ __launch_bounds__(256) void cls_kernel(
    const float* __restrict__ pooled, const float* __restrict__ w1,
    const float* __restrict__ b1, const float* __restrict__ lg, const float* __restrict__ lb,
    const float* __restrict__ w2, const float* __restrict__ b2, float* __restrict__ outp)
{
    int b = blockIdx.x, j = threadIdx.x;
    __shared__ float pv[256];
    __shared__ float red[8];
    pv[j] = pooled[b*256 + j];
    __syncthreads();
    float acc = b1[j];
    for (int d=0; d<256; d+=4){
        float4 p4 = *(const float4*)&pv[d];
        const float* wr = &w1[(size_t)j*256 + d];
        acc += p4.x*wr[0] + p4.y*wr[1] + p4.z*wr[2] + p4.w*wr[3];
    }
    float s = acc, q = acc*acc;
    #pragma unroll
    for (int m=32;m>=1;m>>=1){ s += __shfl_xor(s,m); q += __shfl_xor(q,m); }
    int wid = j>>6;
    if ((j&63)==0){ red[wid]=s; red[4+wid]=q; }
    __syncthreads();
    s = red[0]+red[1]+red[2]+red[3]; q = red[4]+red[5]+red[6]+red[7];
    float mean = s*(1.f/256.f), var = q*(1.f/256.f)-mean*mean, rstd = rsqrtf(var+1e-5f);
    float h1v = fmaxf((acc-mean)*rstd*lg[j]+lb[j], 0.f);
    float pr = h1v * w2[j];
    __syncthreads();
    #pragma unroll
    for (int m=32;m>=1;m>>=1) pr += __shfl_xor(pr,m);
    if ((j&63)==0) red[wid] = pr;
    __syncthreads();
    if (j==0) outp[b] = red[0]+red[1]+red[2]+red[3] + b2[0];
}

// ==========================================================================
extern "C" void kernel_launch(void* const* d_in, const int* in_sizes, int n_in,
                              void* d_out, int out_size, void* d_ws, size_t ws_size,
                              hipStream_t stream)
{
    const float* x       = (const float*)d_in[0];
    const int*   lengths = (const int*)  d_in[1];
    const float* fe_w    = (const float*)d_in[2];
    const float* fe_b    = (const float*)d_in[3];
    const float* fe_ln_g = (const float*)d_in[4];
    const float* fe_ln_b = (const float*)d_in[5];
    const float* w_ih    = (const float*)d_in[6];
    const float* w_hh    = (const float*)d_in[7];
    const float* b_ih    = (const float*)d_in[8];
    const float* b_hh    = (const float*)d_in[9];
    const float* attn_w  = (const float*)d_in[10];
    const float* attn_b  = (const float*)d_in[11];
    const float* attn_ow = (const float*)d_in[12];
    const float* attn_ob = (const float*)d_in[13];
    const float* ln1_g   = (const float*)d_in[14];
    const float* ln1_b   = (const float*)d_in[15];
    const float* router_w= (const float*)d_in[16];
    const float* e_w1    = (const float*)d_in[17];
    const float* e_b1    = (const float*)d_in[18];
    const float* e_w2    = (const float*)d_in[19];
    const float* e_b2    = (const float*)d_in[20];
    const float* ln2_g   = (const float*)d_in[21];
    const float* ln2_b   = (const float*)d_in[22];
    const float* cl_w1   = (const float*)d_in[23];
    const float* cl_b1   = (const float*)d_in[24];
    const float* cl_ln_g = (const float*)d_in[25];
    const float* cl_ln_b = (const float*)d_in[26];
    const float* cl_w2   = (const float*)d_in[27];
    const float* cl_b2   = (const float*)d_in[28];
    float* outp = (float*)d_out;

    // workspace layout (floats)
    const size_t NEED = (size_t)50381832 * 4;
    if (ws_size < NEED){
        fprintf(stderr, "kernel_launch: ws too small (%zu < %zu)\n", ws_size, NEED);
        return;
    }
    float* W     = (float*)d_ws;
    float* h0    = W;                    // [T,256]   32MB
    float* Zx    = W + 8388608;          // [T,1024] 128MB
    float* lstm  = W + 41943040;         // [T,256]   32MB
    float* hglob = W + 50331648;         // [2,64,2,128]
    float* pooled= W + 50364416;         // [64,256]
    float* bcomb = W + 50380800;         // [1024]
    // aliases into dead regions
    float* qkv  = Zx;                    // [T,768] (after LSTM consumes Zx)
    float* ctx  = Zx + 25165824;         // [T,256]
    float* aop  = h0;                    // [T,256] (h0 dead after Zx GEMM)
    float* src  = lstm;                  // LN1 in-place
    float* out2 = Zx;                    // [T,256] (qkv/ctx dead)
    // MoE scratch aliases (h0 region dead after ln1 consumes aop)
    float*    gates  = h0;               // [32768]
    int*      bucket = (int*)(h0 + 32768);       // [5*32768]
    unsigned* cnt    = (unsigned*)pooled;        // [8] (pooled written later)

    prep_kernel<<<dim3(128), 256, 0, stream>>>(b_ih, b_hh, bcomb, hglob, cnt);
    // feature extractor GEMM + LN + ReLU
    gemm_mfma<<<dim3(2,256), 256, 0, stream>>>(x, fe_w, fe_b, h0, 256, lengths);
    ln_act<<<dim3(32768), 256, 0, stream>>>(h0, nullptr, fe_ln_g, fe_ln_b, lengths, 1);
    // LSTM input projection for all timesteps
    gemm_mfma<<<dim3(8,256), 256, 0, stream>>>(h0, w_ih, bcomb, Zx, 1024, lengths);
    // recurrent LSTM
    lstm_kernel<<<dim3(128), 512, 0, stream>>>(Zx, w_hh, lengths, hglob, lstm);
    // attention
    gemm_mfma<<<dim3(6,256), 256, 0, stream>>>(lstm, attn_w, attn_b, qkv, 768, lengths);
    attn_kernel<<<dim3(512), 256, 0, stream>>>(qkv, lengths, ctx);
    gemm_mfma<<<dim3(2,256), 256, 0, stream>>>(ctx, attn_ow, attn_ob, aop, 256, lengths);
    // post-norm residual LN1 (in-place into lstm -> src)
    ln_act<<<dim3(32768), 256, 0, stream>>>(src, aop, ln1_g, ln1_b, lengths, 0);
    // MoE: route then expert-batched GEMM (+gate+residual+LN2)
    route_kernel<<<dim3(8192), 256, 0, stream>>>(src, router_w, lengths, cnt, bucket, gates);
    moe_gemm<<<dim3(512,5), 256, 0, stream>>>(src, bucket, cnt, gates,
                                              e_w1, e_b1, e_w2, e_b2, ln2_g, ln2_b, out2);
    // masked mean pool + classifier
    pool_kernel<<<dim3(64), 1024, 0, stream>>>(out2, lengths, pooled);
    cls_kernel<<<dim3(64), 256, 0, stream>>>(pooled, cl_w1, cl_b1, cl_ln_g, cl_ln_b,
                                             cl_w2, cl_b2, outp);
}

// Round 8
// 1770.283 us; speedup vs baseline: 2.1354x; 1.1399x over previous
//
#include <hip/hip_runtime.h>
#include <cstdio>
#include <math.h>

// Problem constants
#define BB 64
#define SS 512
#define HH 256
#define G4 1024   // 4*H
#define TT (BB*SS)  // 32768

typedef _Float16 h2 __attribute__((ext_vector_type(2)));
typedef _Float16 h4 __attribute__((ext_vector_type(4)));
typedef _Float16 h8 __attribute__((ext_vector_type(8)));
typedef float f4v __attribute__((ext_vector_type(4)));

__device__ __forceinline__ float sigf(float x){ return 1.0f/(1.0f+expf(-x)); }

// -------------------- prep: combined LSTM bias + zero h exchange + cnt -----
__global__ void prep_kernel(const float* __restrict__ b_ih, const float* __restrict__ b_hh,
                            float* __restrict__ bcomb, float* __restrict__ hglob,
                            unsigned* __restrict__ cnt){
    int i = blockIdx.x*blockDim.x + threadIdx.x;
    if (i < G4) bcomb[i] = b_ih[i] + b_hh[i];
    if (i < 8)  cnt[i] = 0u;
    hglob[i] = 0.f;                       // 128 blocks x 256 = 32768 = 2*64*2*128
}

// -------------------- fp16 MFMA GEMM: C[M,N] = A[M,K] * B[N,K]^T + bias ----
// K=256 fixed. 128x128 tile, 256 threads = 4 waves (2x2 quadrants), BK=32.
__global__ __launch_bounds__(256) void gemm_mfma(
    const float* __restrict__ A, const float* __restrict__ Bw,
    const float* __restrict__ bias, float* __restrict__ C,
    int N, const int* __restrict__ lengths)
{
    int m0 = blockIdx.y * 128, n0 = blockIdx.x * 128;
    if (lengths){ int b = m0 >> 9, t0 = m0 & 511; if (t0 >= lengths[b]) return; }
    __shared__ _Float16 Asd[128][40];
    __shared__ _Float16 Bsd[128][40];
    int tid = threadIdx.x;
    int wave = tid >> 6, lane = tid & 63;
    int wr = (wave >> 1) * 64, wc = (wave & 1) * 64;
    int fr = lane & 15, fk = (lane >> 4) * 8;
    int srow = tid >> 1, skh = (tid & 1) * 16;
    const float* gA = A  + (size_t)(m0 + srow)*256 + skh;
    const float* gB = Bw + (size_t)(n0 + srow)*256 + skh;
    f4v acc[4][4];
    #pragma unroll
    for (int i=0;i<4;i++)
        #pragma unroll
        for (int j=0;j<4;j++) acc[i][j] = (f4v){0.f,0.f,0.f,0.f};

    for (int kt = 0; kt < 8; ++kt){
        int k0 = kt*32;
        float4 a0 = *(const float4*)(gA + k0);
        float4 a1 = *(const float4*)(gA + k0 + 4);
        float4 a2 = *(const float4*)(gA + k0 + 8);
        float4 a3 = *(const float4*)(gA + k0 + 12);
        float4 b0 = *(const float4*)(gB + k0);
        float4 b1 = *(const float4*)(gB + k0 + 4);
        float4 b2 = *(const float4*)(gB + k0 + 8);
        float4 b3 = *(const float4*)(gB + k0 + 12);
        __syncthreads();   // previous iter's frag reads complete
        {
            _Float16* da = &Asd[srow][skh];
            h2 t;
            t.x=(_Float16)a0.x; t.y=(_Float16)a0.y; *(h2*)(da+0)=t;
            t.x=(_Float16)a0.z; t.y=(_Float16)a0.w; *(h2*)(da+2)=t;
            t.x=(_Float16)a1.x; t.y=(_Float16)a1.y; *(h2*)(da+4)=t;
            t.x=(_Float16)a1.z; t.y=(_Float16)a1.w; *(h2*)(da+6)=t;
            t.x=(_Float16)a2.x; t.y=(_Float16)a2.y; *(h2*)(da+8)=t;
            t.x=(_Float16)a2.z; t.y=(_Float16)a2.w; *(h2*)(da+10)=t;
            t.x=(_Float16)a3.x; t.y=(_Float16)a3.y; *(h2*)(da+12)=t;
            t.x=(_Float16)a3.z; t.y=(_Float16)a3.w; *(h2*)(da+14)=t;
            _Float16* db = &Bsd[srow][skh];
            t.x=(_Float16)b0.x; t.y=(_Float16)b0.y; *(h2*)(db+0)=t;
            t.x=(_Float16)b0.z; t.y=(_Float16)b0.w; *(h2*)(db+2)=t;
            t.x=(_Float16)b1.x; t.y=(_Float16)b1.y; *(h2*)(db+4)=t;
            t.x=(_Float16)b1.z; t.y=(_Float16)b1.w; *(h2*)(db+6)=t;
            t.x=(_Float16)b2.x; t.y=(_Float16)b2.y; *(h2*)(db+8)=t;
            t.x=(_Float16)b2.z; t.y=(_Float16)b2.w; *(h2*)(db+10)=t;
            t.x=(_Float16)b3.x; t.y=(_Float16)b3.y; *(h2*)(db+12)=t;
            t.x=(_Float16)b3.z; t.y=(_Float16)b3.w; *(h2*)(db+14)=t;
        }
        __syncthreads();   // stage complete
        h8 af[4], bf[4];
        #pragma unroll
        for (int mt=0;mt<4;mt++) af[mt] = *(const h8*)&Asd[wr + mt*16 + fr][fk];
        #pragma unroll
        for (int nt=0;nt<4;nt++) bf[nt] = *(const h8*)&Bsd[wc + nt*16 + fr][fk];
        #pragma unroll
        for (int mt=0;mt<4;mt++)
            #pragma unroll
            for (int nt=0;nt<4;nt++)
                acc[mt][nt] = __builtin_amdgcn_mfma_f32_16x16x32_f16(af[mt], bf[nt], acc[mt][nt], 0,0,0);
    }
    int rbase = m0 + wr + (lane>>4)*4;
    #pragma unroll
    for (int nt=0;nt<4;nt++){
        int col = n0 + wc + nt*16 + fr;
        float bv = bias ? bias[col] : 0.f;
        #pragma unroll
        for (int mt=0;mt<4;mt++){
            int row = rbase + mt*16;
            #pragma unroll
            for (int j=0;j<4;j++)
                C[(size_t)(row+j)*N + col] = acc[mt][nt][j] + bv;
        }
    }
}

// -------------------- per-row LayerNorm (optional residual add, optional ReLU)
__global__ __launch_bounds__(256) void ln_act(
    float* __restrict__ X, const float* __restrict__ add,
    const float* __restrict__ gg, const float* __restrict__ bb,
    const int* __restrict__ lengths, int relu)
{
    int row = blockIdx.x;
    { int b = row >> 9, t = row & 511; if (t >= lengths[b]) return; }
    int tid = threadIdx.x;
    __shared__ float red[8];
    size_t idx = (size_t)row*HH + tid;
    float v = X[idx];
    if (add) v += add[idx];
    float s = v, q = v*v;
    #pragma unroll
    for (int m=32;m>=1;m>>=1){ s += __shfl_xor(s,m); q += __shfl_xor(q,m); }
    if ((tid&63)==0){ red[tid>>6]=s; red[4+(tid>>6)]=q; }
    __syncthreads();
    s = red[0]+red[1]+red[2]+red[3]; q = red[4]+red[5]+red[6]+red[7];
    float mean = s*(1.f/HH);
    float var  = q*(1.f/HH) - mean*mean;
    float rstd = rsqrtf(var + 1e-5f);
    float o = (v-mean)*rstd*gg[tid] + bb[tid];
    if (relu) o = fmaxf(o, 0.f);
    X[idx] = o;
}

// -------------------- LSTM: 128 blocks = 64 rows x 2 hidden-partitions ----
// z-GEMM via MFMA: W slice lives in VGPRs as 32 A-fragments (128 VGPRs);
// h broadcast as replicated B-fragments (8 ds_read_b128 per wave per step).
// 512 threads = 8 waves; wave w owns z-columns [w*64, w*64+64).
// Waves 0-1 (tid<128): gate math + publish + Zx prefetch. Wave 4
// (tid 256..319): pollers (clean vmcnt). 2 lgkm-only barriers per step.
__global__ __launch_bounds__(512) void lstm_kernel(
    const float* __restrict__ Zx, const float* __restrict__ whh,
    const int* __restrict__ lengths, float* __restrict__ hglob,
    float* __restrict__ out)
{
    int bid = blockIdx.x;
    int row = bid >> 1, p = bid & 1;
    int tid = threadIdx.x;
    int wv = tid >> 6, lane = tid & 63;
    int lr = lane & 15, lg = lane >> 4;
    __shared__ __align__(16) _Float16 hs[256];
    __shared__ __align__(16) float zfull[512];

    // W fragments: rowtile i (cols (wv*4+i)*16 + lr), k-slice kt*32 + lg*8
    h8 wfrag[4][8];
    #pragma unroll
    for (int i=0;i<4;i++){
        int c = (wv*4+i)*16 + lr;           // local z column
        int q = c >> 7, dd = c & 127;
        const float* wr_ = whh + (size_t)(q*256 + p*128 + dd)*256;
        #pragma unroll
        for (int kt=0;kt<8;kt++){
            const float* src = wr_ + kt*32 + lg*8;
            float4 w0 = *(const float4*)(src);
            float4 w1 = *(const float4*)(src+4);
            h8 f;
            f[0]=(_Float16)w0.x; f[1]=(_Float16)w0.y; f[2]=(_Float16)w0.z; f[3]=(_Float16)w0.w;
            f[4]=(_Float16)w1.x; f[5]=(_Float16)w1.y; f[6]=(_Float16)w1.z; f[7]=(_Float16)w1.w;
            wfrag[i][kt] = f;
        }
    }
    int Tg = lengths[row];
    float creg = 0.f;

    if (tid < 128) ((unsigned*)hs)[tid] = 0u;
    __syncthreads();

    // Zx prefetch for gate threads (tid<128 -> dim dd = tid)
    float zx0=0.f, zx1=0.f, zx2=0.f, zx3=0.f;
    size_t zbase = (size_t)row*SS*G4 + (size_t)(p*128 + tid);
    if (tid < 128 && Tg > 0){
        zx0 = Zx[zbase      ];
        zx1 = Zx[zbase + 256];
        zx2 = Zx[zbase + 512];
        zx3 = Zx[zbase + 768];
    }
    unsigned long long* hgl64 = (unsigned long long*)hglob;
    int pt = tid - 256;                      // poller index 0..63 (wave 4)

    for (int s = 0; s < Tg; ++s){
        asm volatile("s_waitcnt lgkmcnt(0)" ::: "memory");
        __builtin_amdgcn_s_barrier();            // D: hs(s) complete
        asm volatile("" ::: "memory");

        // h fragments (broadcast; lanes with same lg share a 16B chunk)
        h8 hfrag[8];
        #pragma unroll
        for (int kt=0;kt<8;kt++)
            hfrag[kt] = *(const h8*)&hs[kt*32 + lg*8];
        // z = W * h via MFMA (cols replicated)
        #pragma unroll
        for (int i=0;i<4;i++){
            f4v zacc = (f4v){0.f,0.f,0.f,0.f};
            #pragma unroll
            for (int kt=0;kt<8;kt++)
                zacc = __builtin_amdgcn_mfma_f32_16x16x32_f16(wfrag[i][kt], hfrag[kt], zacc, 0,0,0);
            if (lr == 0)
                *(f4v*)&zfull[(wv*4+i)*16 + lg*4] = zacc;
        }
        asm volatile("s_waitcnt lgkmcnt(0)" ::: "memory");
        __builtin_amdgcn_s_barrier();            // E: zfull ready
        asm volatile("" ::: "memory");

        int buf2 = (s+1) & 1;
        unsigned tag2 = (((unsigned)(s+1)) & 7u) ^ 5u;
        if (tid < 128){
            float z0 = zfull[tid      ] + zx0;
            float z1 = zfull[128 + tid] + zx1;
            float z2 = zfull[256 + tid] + zx2;
            float z3 = zfull[384 + tid] + zx3;
            if (s+1 < Tg){
                size_t zb = zbase + (size_t)(s+1)*G4;
                zx0 = Zx[zb      ];
                zx1 = Zx[zb + 256];
                zx2 = Zx[zb + 512];
                zx3 = Zx[zb + 768];
            }
            creg = sigf(z1)*creg + sigf(z0)*tanhf(z2);
            float hvv = sigf(z3)*tanhf(creg);
            unsigned hb = (__float_as_uint(hvv) & ~7u) | tag2;
            float hm = __uint_as_float(hb);
            __hip_atomic_store(&hglob[((size_t)(buf2*64 + row)*2 + p)*128 + tid],
                               hm, __ATOMIC_RELAXED, __HIP_MEMORY_SCOPE_AGENT);
            out[((size_t)row*SS + s)*HH + p*128 + tid] = hvv;
            hs[p*128 + tid] = (_Float16)hm;
        } else if (wv == 4 && (s+1) < Tg){
            // poll partner slice for step s+1 (64 u64 = 128 halves)
            size_t paddr = ((size_t)(buf2*64 + row)*2 + (1-p))*64 + pt;
            unsigned long long pv = __hip_atomic_load(&hgl64[paddr], __ATOMIC_RELAXED, __HIP_MEMORY_SCOPE_AGENT);
            while ((((unsigned)pv & 7u) != tag2) || (((unsigned)(pv>>32) & 7u) != tag2))
                pv = __hip_atomic_load(&hgl64[paddr], __ATOMIC_RELAXED, __HIP_MEMORY_SCOPE_AGENT);
            h2 t; t.x = (_Float16)__uint_as_float((unsigned)pv);
            t.y = (_Float16)__uint_as_float((unsigned)(pv>>32));
            ((h2*)hs)[(1-p)*64 + pt] = t;
        }
    }
}

// -------------------- MFMA flash attention: block per (b,head) ------------
// 256 threads = 4 waves. S^T = mfma(K, Q) so lane's column = one q-row;
// online softmax in-register; PV via 16x16x16 with V transposed in LDS.
__global__ __launch_bounds__(256) void attn_kernel(
    const float* __restrict__ qkv, const int* __restrict__ lengths, float* __restrict__ ctx)
{
    int bh = blockIdx.x; int b = bh >> 3, h = bh & 7;
    int len = lengths[b];
    int tid = threadIdx.x;
    int wv = tid >> 6, lane = tid & 63;
    int lr = lane & 15, lg = lane >> 4;
    __shared__ _Float16 Ks[512][32];      // [key][d] fp16
    __shared__ _Float16 Vt[32][512];      // [d][key] fp16 (transposed)

    // stage K row-major + V transposed (fp32 -> fp16)
    #pragma unroll
    for (int j = 0; j < 16; ++j){
        int c = tid + j*256;              // float4 chunk id (4096 total)
        int key = c >> 3, d4 = (c & 7) * 4;
        size_t base = ((size_t)b*512 + key)*768 + h*32 + d4;
        float4 kv = *(const float4*)&qkv[base + 256];
        float4 vvv = *(const float4*)&qkv[base + 512];
        h2 k0; k0.x=(_Float16)kv.x; k0.y=(_Float16)kv.y;
        h2 k1; k1.x=(_Float16)kv.z; k1.y=(_Float16)kv.w;
        *(h2*)&Ks[key][d4]   = k0;
        *(h2*)&Ks[key][d4+2] = k1;
        Vt[d4+0][key] = (_Float16)vvv.x;
        Vt[d4+1][key] = (_Float16)vvv.y;
        Vt[d4+2][key] = (_Float16)vvv.z;
        Vt[d4+3][key] = (_Float16)vvv.w;
    }
    __syncthreads();

    // Q fragments (8 q-tiles per wave: qt = wv + 4*i), col = q = qt*16+lr
    h8 qf[8];
    #pragma unroll
    for (int i=0;i<8;i++){
        int qt = wv + 4*i;
        int q = qt*16 + lr;
        size_t qb = ((size_t)b*512 + q)*768 + h*32 + lg*8;
        float4 q0 = *(const float4*)&qkv[qb];
        float4 q1 = *(const float4*)&qkv[qb+4];
        h8 f;
        f[0]=(_Float16)q0.x; f[1]=(_Float16)q0.y; f[2]=(_Float16)q0.z; f[3]=(_Float16)q0.w;
        f[4]=(_Float16)q1.x; f[5]=(_Float16)q1.y; f[6]=(_Float16)q1.z; f[7]=(_Float16)q1.w;
        qf[i] = f;
    }
    f4v oacc[8][2];
    float mrow[8], lrow[8];
    #pragma unroll
    for (int i=0;i<8;i++){
        oacc[i][0]=(f4v){0.f,0.f,0.f,0.f}; oacc[i][1]=(f4v){0.f,0.f,0.f,0.f};
        mrow[i] = -3.0e38f; lrow[i] = 0.f;
    }
    const float sc = 0.1767766952966369f;    // 1/sqrt(32)
    int ktmax = (len + 15) >> 4;
    for (int kt = 0; kt < ktmax; ++kt){
        h8 kf = *(const h8*)&Ks[kt*16 + lr][lg*8];      // A: K[key=kt*16+lr][d-slice]
        int keybase = kt*16 + lg*4;
        h4 vf0, vf1;                                     // A: V^T[d][key-slice]
        #pragma unroll
        for (int j=0;j<4;j++){
            vf0[j] = Vt[lr][keybase + j];
            vf1[j] = Vt[16+lr][keybase + j];
        }
        #pragma unroll
        for (int i=0;i<8;i++){
            int qt = wv + 4*i;
            if (qt*16 >= len) continue;                  // wave-uniform
            f4v s4 = __builtin_amdgcn_mfma_f32_16x16x32_f16(kf, qf[i], (f4v){0.f,0.f,0.f,0.f}, 0,0,0);
            float s0 = s4[0]*sc, s1 = s4[1]*sc, s2 = s4[2]*sc, s3 = s4[3]*sc;
            if (keybase+0 >= len) s0 = -3.0e38f;
            if (keybase+1 >= len) s1 = -3.0e38f;
            if (keybase+2 >= len) s2 = -3.0e38f;
            if (keybase+3 >= len) s3 = -3.0e38f;
            float mt = fmaxf(fmaxf(s0,s1), fmaxf(s2,s3));
            mt = fmaxf(mt, __shfl_xor(mt, 16));
            mt = fmaxf(mt, __shfl_xor(mt, 32));
            float mnew = fmaxf(mrow[i], mt);
            float scale = __expf(mrow[i] - mnew);
            float p0 = __expf(s0 - mnew), p1 = __expf(s1 - mnew);
            float p2 = __expf(s2 - mnew), p3 = __expf(s3 - mnew);
            float psum = p0+p1+p2+p3;
            psum += __shfl_xor(psum, 16);
            psum += __shfl_xor(psum, 32);
            lrow[i] = lrow[i]*scale + psum;
            mrow[i] = mnew;
            oacc[i][0] = oacc[i][0] * scale;
            oacc[i][1] = oacc[i][1] * scale;
            h4 pf; pf[0]=(_Float16)p0; pf[1]=(_Float16)p1; pf[2]=(_Float16)p2; pf[3]=(_Float16)p3;
            oacc[i][0] = __builtin_amdgcn_mfma_f32_16x16x16f16(vf0, pf, oacc[i][0], 0,0,0);
            oacc[i][1] = __builtin_amdgcn_mfma_f32_16x16x16f16(vf1, pf, oacc[i][1], 0,0,0);
        }
    }
    // write ctx: lane holds O^T[d = dt*16 + lg*4+j][q = qt*16+lr]
    #pragma unroll
    for (int i=0;i<8;i++){
        int qt = wv + 4*i;
        if (qt*16 >= len) continue;
        int q = qt*16 + lr;
        float inv = 1.0f / lrow[i];
        size_t cb = ((size_t)b*512 + q)*256 + h*32;
        #pragma unroll
        for (int j=0;j<4;j++){
            ctx[cb + lg*4 + j]      = oacc[i][0][j]*inv;
            ctx[cb + 16 + lg*4 + j] = oacc[i][1][j]*inv;
        }
    }
}

// -------------------- MoE routing: one wave per token (coalesced) ---------
__global__ __launch_bounds__(256) void route_kernel(
    const float* __restrict__ src, const float* __restrict__ rw,
    const int* __restrict__ lengths, unsigned* __restrict__ cnt,
    int* __restrict__ bucket, float* __restrict__ gates)
{
    int wv = threadIdx.x >> 6, lane = threadIdx.x & 63;
    int tok = blockIdx.x*4 + wv;
    int b = tok >> 9, t = tok & 511;
    if (t >= lengths[b]) return;
    float4 xv = *(const float4*)&src[(size_t)tok*256 + lane*4];
    float l0,l1,l2,l3,l4;
    {
        const float* r0 = &rw[(lane*4)*5];
        l0 = xv.x*r0[0] + xv.y*r0[5] + xv.z*r0[10] + xv.w*r0[15];
        l1 = xv.x*r0[1] + xv.y*r0[6] + xv.z*r0[11] + xv.w*r0[16];
        l2 = xv.x*r0[2] + xv.y*r0[7] + xv.z*r0[12] + xv.w*r0[17];
        l3 = xv.x*r0[3] + xv.y*r0[8] + xv.z*r0[13] + xv.w*r0[18];
        l4 = xv.x*r0[4] + xv.y*r0[9] + xv.z*r0[14] + xv.w*r0[19];
    }
    #pragma unroll
    for (int m=32;m>=1;m>>=1){
        l0 += __shfl_xor(l0,m); l1 += __shfl_xor(l1,m); l2 += __shfl_xor(l2,m);
        l3 += __shfl_xor(l3,m); l4 += __shfl_xor(l4,m);
    }
    if (lane == 0){
        float mx = l0; int ix = 0;
        if (l1 > mx){ mx=l1; ix=1; }
        if (l2 > mx){ mx=l2; ix=2; }
        if (l3 > mx){ mx=l3; ix=3; }
        if (l4 > mx){ mx=l4; ix=4; }
        float ssum = expf(l0-mx)+expf(l1-mx)+expf(l2-mx)+expf(l3-mx)+expf(l4-mx);
        int slot = (int)atomicAdd(&cnt[ix], 1u);
        bucket[ix*32768 + slot] = tok;
        gates[tok] = 1.0f/ssum;
    }
}

// -------------------- MoE expert-batched GEMM + gate + residual + LN2 -----
__global__ __launch_bounds__(256) void moe_gemm(
    const float* __restrict__ src, const int* __restrict__ bucket,
    const unsigned* __restrict__ cnt, const float* __restrict__ gates,
    const float* __restrict__ w1, const float* __restrict__ b1,
    const float* __restrict__ w2, const float* __restrict__ b2,
    const float* __restrict__ g2, const float* __restrict__ bt2,
    float* __restrict__ out)
{
    int e = blockIdx.y;
    int count = (int)cnt[e];
    int start = blockIdx.x*64;
    if (start >= count) return;
    int n = min(64, count-start);
    __shared__ float sv[64][256];
    __shared__ float hv[64][256];
    __shared__ int   toks[64];
    __shared__ float gts[64];
    int tid = threadIdx.x;
    if (tid < 64){
        int idx = start + min(tid, n-1);
        int tk = bucket[e*32768 + idx];
        toks[tid] = tk;
        gts[tid]  = gates[tk];
    }
    __syncthreads();
    for (int i=0;i<64;i++)
        sv[i][tid] = src[(size_t)toks[i]*256 + tid];
    __syncthreads();
    int tt = tid >> 5, dd = tid & 31;
    const float* W1 = w1 + (size_t)e*65536;
    const float* W2 = w2 + (size_t)e*65536;
    float acc[8][8];
    {
        float4 bA = *(const float4*)&b1[e*256 + dd*8];
        float4 bB = *(const float4*)&b1[e*256 + dd*8 + 4];
        #pragma unroll
        for (int i=0;i<8;i++){
            acc[i][0]=bA.x; acc[i][1]=bA.y; acc[i][2]=bA.z; acc[i][3]=bA.w;
            acc[i][4]=bB.x; acc[i][5]=bB.y; acc[i][6]=bB.z; acc[i][7]=bB.w;
        }
    }
    #pragma unroll 2
    for (int k=0;k<256;k++){
        float4 wA = *(const float4*)&W1[(size_t)k*256 + dd*8];
        float4 wB = *(const float4*)&W1[(size_t)k*256 + dd*8 + 4];
        float wv0=wA.x,wv1=wA.y,wv2=wA.z,wv3=wA.w,wv4=wB.x,wv5=wB.y,wv6=wB.z,wv7=wB.w;
        #pragma unroll
        for (int i=0;i<8;i++){
            float hvv = sv[tt*8+i][k];
            acc[i][0]=fmaf(hvv,wv0,acc[i][0]); acc[i][1]=fmaf(hvv,wv1,acc[i][1]);
            acc[i][2]=fmaf(hvv,wv2,acc[i][2]); acc[i][3]=fmaf(hvv,wv3,acc[i][3]);
            acc[i][4]=fmaf(hvv,wv4,acc[i][4]); acc[i][5]=fmaf(hvv,wv5,acc[i][5]);
            acc[i][6]=fmaf(hvv,wv6,acc[i][6]); acc[i][7]=fmaf(hvv,wv7,acc[i][7]);
        }
    }
    #pragma unroll
    for (int i=0;i<8;i++){
        #pragma unroll
        for (int j=0;j<8;j++) hv[tt*8+i][dd*8+j] = fmaxf(acc[i][j], 0.f);
    }
    __syncthreads();
    {
        float4 bA = *(const float4*)&b2[e*256 + dd*8];
        float4 bB = *(const float4*)&b2[e*256 + dd*8 + 4];
        #pragma unroll
        for (int i=0;i<8;i++){
            acc[i][0]=bA.x; acc[i][1]=bA.y; acc[i][2]=bA.z; acc[i][3]=bA.w;
            acc[i][4]=bB.x; acc[i][5]=bB.y; acc[i][6]=bB.z; acc[i][7]=bB.w;
        }
    }
    #pragma unroll 2
    for (int k=0;k<256;k++){
        float4 wA = *(const float4*)&W2[(size_t)k*256 + dd*8];
        float4 wB = *(const float4*)&W2[(size_t)k*256 + dd*8 + 4];
        float wv0=wA.x,wv1=wA.y,wv2=wA.z,wv3=wA.w,wv4=wB.x,wv5=wB.y,wv6=wB.z,wv7=wB.w;
        #pragma unroll
        for (int i=0;i<8;i++){
            float hvv = hv[tt*8+i][k];
            acc[i][0]=fmaf(hvv,wv0,acc[i][0]); acc[i][1]=fmaf(hvv,wv1,acc[i][1]);
            acc[i][2]=fmaf(hvv,wv2,acc[i][2]); acc[i][3]=fmaf(hvv,wv3,acc[i][3]);
            acc[i][4]=fmaf(hvv,wv4,acc[i][4]); acc[i][5]=fmaf(hvv,wv5,acc[i][5]);
            acc[i][6]=fmaf(hvv,wv6,acc[i][6]); acc[i][7]=fmaf(hvv,wv7,acc[i][7]);
        }
    }
    float4 gA = *(const float4*)&g2[dd*8];
    float4 gB = *(const float4*)&g2[dd*8 + 4];
    float4 tA = *(const float4*)&bt2[dd*8];
    float4 tB = *(const float4*)&bt2[dd*8 + 4];
    float gv[8] = {gA.x,gA.y,gA.z,gA.w,gB.x,gB.y,gB.z,gB.w};
    float tv[8] = {tA.x,tA.y,tA.z,tA.w,tB.x,tB.y,tB.z,tB.w};
    #pragma unroll
    for (int i=0;i<8;i++){
        float gate = gts[tt*8+i];
        float4 sA = *(const float4*)&sv[tt*8+i][dd*8];
        float4 sB = *(const float4*)&sv[tt*8+i][dd*8 + 4];
        float svv[8] = {sA.x,sA.y,sA.z,sA.w,sB.x,sB.y,sB.z,sB.w};
        float s = 0.f, q = 0.f;
        #pragma unroll
        for (int j=0;j<8;j++){
            float r = svv[j] + gate*acc[i][j];
            acc[i][j] = r;
            s += r; q += r*r;
        }
        #pragma unroll
        for (int m=16;m>=1;m>>=1){ s += __shfl_xor(s,m); q += __shfl_xor(q,m); }
        float mean = s*(1.f/256.f), var = q*(1.f/256.f)-mean*mean;
        float rstd = rsqrtf(var + 1e-5f);
        if (tt*8+i < n){
            int tok = toks[tt*8+i];
            float o[8];
            #pragma unroll
            for (int j=0;j<8;j++) o[j] = (acc[i][j]-mean)*rstd*gv[j] + tv[j];
            float4 oA = make_float4(o[0],o[1],o[2],o[3]);
            float4 oB = make_float4(o[4],o[5],o[6],o[7]);
            *(float4*)&out[(size_t)tok*256 + dd*8]     = oA;
            *(float4*)&out[(size_t)tok*256 + dd*8 + 4] = oB;
        }
    }
}

// -------------------- masked mean pool (1024 threads, 4-way t-split) ------
__global__ __launch_bounds__(1024) void pool_kernel(
    const float* __restrict__ out2, const int* __restrict__ lengths, float* __restrict__ pooled)
{
    int b = blockIdx.x;
    int d = threadIdx.x & 255, c = threadIdx.x >> 8;
    int len = lengths[b];
    __shared__ float part[4][256];
    float s = 0.f;
    for (int t=c; t<len; t+=4) s += out2[((size_t)b*512+t)*256 + d];
    part[c][d] = s;
    __syncthreads();
    if (c==0) pooled[b*256+d] = (part[0][d]+part[1][d]+part[2][d]+part[3][d]) / (float)len;
}

// -------------------- classifier head -------------------------------------
__global__ __launch_bounds__(256) void cls_kernel(
    const float* __restrict__ pooled, const float* __restrict__ w1,
    const float* __restrict__ b1, const float* __restrict__ lg, const float* __restrict__ lb,
    const float* __restrict__ w2, const float* __restrict__ b2, float* __restrict__ outp)
{
    int b = blockIdx.x, j = threadIdx.x;
    __shared__ float pv[256];
    __shared__ float red[8];
    pv[j] = pooled[b*256 + j];
    __syncthreads();
    float acc = b1[j];
    for (int d=0; d<256; d+=4){
        float4 p4 = *(const float4*)&pv[d];
        const float* wr = &w1[(size_t)j*256 + d];
        acc += p4.x*wr[0] + p4.y*wr[1] + p4.z*wr[2] + p4.w*wr[3];
    }
    float s = acc, q = acc*acc;
    #pragma unroll
    for (int m=32;m>=1;m>>=1){ s += __shfl_xor(s,m); q += __shfl_xor(q,m); }
    int wid = j>>6;
    if ((j&63)==0){ red[wid]=s; red[4+wid]=q; }
    __syncthreads();
    s = red[0]+red[1]+red[2]+red[3]; q = red[4]+red[5]+red[6]+red[7];
    float mean = s*(1.f/256.f), var = q*(1.f/256.f)-mean*mean, rstd = rsqrtf(var+1e-5f);
    float h1v = fmaxf((acc-mean)*rstd*lg[j]+lb[j], 0.f);
    float pr = h1v * w2[j];
    __syncthreads();
    #pragma unroll
    for (int m=32;m>=1;m>>=1) pr += __shfl_xor(pr,m);
    if ((j&63)==0) red[wid] = pr;
    __syncthreads();
    if (j==0) outp[b] = red[0]+red[1]+red[2]+red[3] + b2[0];
}

// ==========================================================================
extern "C" void kernel_launch(void* const* d_in, const int* in_sizes, int n_in,
                              void* d_out, int out_size, void* d_ws, size_t ws_size,
                              hipStream_t stream)
{
    const float* x       = (const float*)d_in[0];
    const int*   lengths = (const int*)  d_in[1];
    const float* fe_w    = (const float*)d_in[2];
    const float* fe_b    = (const float*)d_in[3];
    const float* fe_ln_g = (const float*)d_in[4];
    const float* fe_ln_b = (const float*)d_in[5];
    const float* w_ih    = (const float*)d_in[6];
    const float* w_hh    = (const float*)d_in[7];
    const float* b_ih    = (const float*)d_in[8];
    const float* b_hh    = (const float*)d_in[9];
    const float* attn_w  = (const float*)d_in[10];
    const float* attn_b  = (const float*)d_in[11];
    const float* attn_ow = (const float*)d_in[12];
    const float* attn_ob = (const float*)d_in[13];
    const float* ln1_g   = (const float*)d_in[14];
    const float* ln1_b   = (const float*)d_in[15];
    const float* router_w= (const float*)d_in[16];
    const float* e_w1    = (const float*)d_in[17];
    const float* e_b1    = (const float*)d_in[18];
    const float* e_w2    = (const float*)d_in[19];
    const float* e_b2    = (const float*)d_in[20];
    const float* ln2_g   = (const float*)d_in[21];
    const float* ln2_b   = (const float*)d_in[22];
    const float* cl_w1   = (const float*)d_in[23];
    const float* cl_b1   = (const float*)d_in[24];
    const float* cl_ln_g = (const float*)d_in[25];
    const float* cl_ln_b = (const float*)d_in[26];
    const float* cl_w2   = (const float*)d_in[27];
    const float* cl_b2   = (const float*)d_in[28];
    float* outp = (float*)d_out;

    // workspace layout (floats)
    const size_t NEED = (size_t)50381832 * 4;
    if (ws_size < NEED){
        fprintf(stderr, "kernel_launch: ws too small (%zu < %zu)\n", ws_size, NEED);
        return;
    }
    float* W     = (float*)d_ws;
    float* h0    = W;                    // [T,256]   32MB
    float* Zx    = W + 8388608;          // [T,1024] 128MB
    float* lstm  = W + 41943040;         // [T,256]   32MB
    float* hglob = W + 50331648;         // [2,64,2,128]
    float* pooled= W + 50364416;         // [64,256]
    float* bcomb = W + 50380800;         // [1024]
    // aliases into dead regions
    float* qkv  = Zx;                    // [T,768] (after LSTM consumes Zx)
    float* ctx  = Zx + 25165824;         // [T,256]
    float* aop  = h0;                    // [T,256] (h0 dead after Zx GEMM)
    float* src  = lstm;                  // LN1 in-place
    float* out2 = Zx;                    // [T,256] (qkv/ctx dead)
    // MoE scratch aliases (h0 region dead after ln1 consumes aop)
    float*    gates  = h0;               // [32768]
    int*      bucket = (int*)(h0 + 32768);       // [5*32768]
    unsigned* cnt    = (unsigned*)pooled;        // [8] (pooled written later)

    prep_kernel<<<dim3(128), 256, 0, stream>>>(b_ih, b_hh, bcomb, hglob, cnt);
    // feature extractor GEMM + LN + ReLU
    gemm_mfma<<<dim3(2,256), 256, 0, stream>>>(x, fe_w, fe_b, h0, 256, lengths);
    ln_act<<<dim3(32768), 256, 0, stream>>>(h0, nullptr, fe_ln_g, fe_ln_b, lengths, 1);
    // LSTM input projection for all timesteps
    gemm_mfma<<<dim3(8,256), 256, 0, stream>>>(h0, w_ih, bcomb, Zx, 1024, lengths);
    // recurrent LSTM
    lstm_kernel<<<dim3(128), 512, 0, stream>>>(Zx, w_hh, lengths, hglob, lstm);
    // attention
    gemm_mfma<<<dim3(6,256), 256, 0, stream>>>(lstm, attn_w, attn_b, qkv, 768, lengths);
    attn_kernel<<<dim3(512), 256, 0, stream>>>(qkv, lengths, ctx);
    gemm_mfma<<<dim3(2,256), 256, 0, stream>>>(ctx, attn_ow, attn_ob, aop, 256, lengths);
    // post-norm residual LN1 (in-place into lstm -> src)
    ln_act<<<dim3(32768), 256, 0, stream>>>(src, aop, ln1_g, ln1_b, lengths, 0);
    // MoE: route then expert-batched GEMM (+gate+residual+LN2)
    route_kernel<<<dim3(8192), 256, 0, stream>>>(src, router_w, lengths, cnt, bucket, gates);
    moe_gemm<<<dim3(512,5), 256, 0, stream>>>(src, bucket, cnt, gates,
                                              e_w1, e_b1, e_w2, e_b2, ln2_g, ln2_b, out2);
    // masked mean pool + classifier
    pool_kernel<<<dim3(64), 1024, 0, stream>>>(out2, lengths, pooled);
    cls_kernel<<<dim3(64), 256, 0, stream>>>(pooled, cl_w1, cl_b1, cl_ln_g, cl_ln_b,
                                             cl_w2, cl_b2, outp);
}